// Round 2
// baseline (294.679 us; speedup 1.0000x reference)
//
#include <hip/hip_runtime.h>
#include <math.h>

// PhysQuadModel: batched RK4 rollout of quadrotor dynamics.
// R7: component-packed (xy) v_pk_f32 + algebra (Jx==Jy wdz hoist, Newton
//     renorm, stage-velocity elimination): 192 -> 125us rocprof.
// R8 (this): TRAJECTORY-PAIR packing. At 1 wave/SIMD wall time tracks the
//   per-wave serial instruction count (~5.5 cyc/inst in R6 AND R7), so the
//   lever is fewer insts/trajectory-step. Packing traj A,B into the two
//   halves of each v_pk op runs the full SCALAR dataflow for two
//   trajectories at once: no swizzle/neg materializations, z-components and
//   combine pack too. ~146 inst/traj-step vs ~215 (est). Extra shaves:
//   v_med3 clamps, rsq reused as 1/|v| in the log map, clamp-folded
//   torque scaling, on-the-fly RK4 weighted accumulation (VGPR control).
//   4096 threads = 64 waves; TLP/ILP can't cut wall (256 serial steps per
//   trajectory, nowhere near issue-capacity), only inst count can.

namespace {
constexpr int   kB    = 8192;
constexpr int   kHalf = 4096;
constexpr int   kN    = 256;
constexpr float kDT   = 0.01f;
constexpr float kMG   = 0.033f * 9.81f;        // M*G
constexpr float kTmax = 1.9f * 0.033f * 9.81f; // 0.6150870
constexpr float kKT   = 3.8e-08f;
constexpr float kKC   = 3.8e-11f;
constexpr float kKTA  = kKT * 0.04f;           // KT*ARM
constexpr float kInvM = 1.0f / 0.033f;
constexpr float kJx   = 1.4e-05f, kJz = 2.17e-05f;
constexpr float kInvJx = 1.0f / 1.4e-05f;
constexpr float kInvJz = 1.0f / 2.17e-05f;
constexpr float kA    = (kJz - kJx) * kInvJx;  // 0.55 (Jx==Jy)
// torque scale folded BEFORE clamp: s = med3(kKTAJ*d, +-kSxyLim)
constexpr float kKTAJ   = kKTA * kInvJx;
constexpr float kKCJ    = kKC * kInvJz;
constexpr float kSxyLim = 0.009f * kInvJx;
constexpr float kSzLim  = 0.002f * kInvJz;
constexpr float kH    = 0.005f;                // 0.5*dt   (omega euler)
constexpr float kHq   = 0.0025f;               // 0.5*dt*0.5 (qd' = 2*qd)
constexpr float kDTq  = 0.005f;                // dt*0.5   (stage-4 quat)
constexpr float kDT6  = 0.0016666667f;         // dt/6
constexpr float kDT6q = 0.5f * kDT6;           // dt/12
constexpr float kVC   = kDT6 * kInvM;          // raw accel -> vel
constexpr float kPC   = kDT6 * kDT * kInvM;    // raw accel -> pos
}

typedef float v2 __attribute__((ext_vector_type(2)));

__device__ __forceinline__ v2 mk2(float a, float b) { v2 r; r.x = a; r.y = b; return r; }
__device__ __forceinline__ float fast_rcp(float x) { return __builtin_amdgcn_rcpf(x); }
__device__ __forceinline__ float fast_rsq(float x) { return __builtin_amdgcn_rsqf(x); }

// per-half med3 clamp (1 inst per half, vs min+max = 2)
__device__ __forceinline__ v2 clamp2(v2 x, float lim) {
  v2 r;
  r.x = __builtin_amdgcn_fmed3f(x.x, -lim, lim);
  r.y = __builtin_amdgcn_fmed3f(x.y, -lim, lim);
  return r;
}

// accurate, used ONCE per trajectory at init
__device__ __forceinline__ void so3_to_quat_init(float rx, float ry, float rz,
                                                 float& qx, float& qy, float& qz, float& qw) {
  float theta = sqrtf(rx * rx + ry * ry + rz * rz);
  float half  = 0.5f * theta;
  float s     = sinf(half);
  float c     = cosf(half);
  float k     = s / (theta + 1e-8f);
  bool  small = theta < 1e-6f;
  k  = small ? 0.5f : k;
  qw = small ? 1.0f : c;
  qx = k * rx; qy = k * ry; qz = k * rz;
}

// One Newton step of rsqrt from y0=1 (|q|^2 = 1+eps, eps small): no trans op.
__device__ __forceinline__ void renorm4(v2& x, v2& y, v2& z, v2& w) {
  v2 n = x * x + y * y + z * z + w * w;
  v2 c = 1.5f - 0.5f * n;
  x *= c; y *= c; z *= c; w *= c;
}

// dyn for the trajectory pair. Raw accel (1/M deferred); qd' = 2*qd with
// qdwn = -qd'_w (sign folded into consumers); wdz stage-invariant (caller).
__device__ __forceinline__ void dyn_pair(
    v2 qx, v2 qy, v2 qz, v2 qw,
    v2 wx, v2 wy, v2 wz,
    v2 T2, v2 TmG, v2 sx, v2 sy,
    v2& ax, v2& ay, v2& az,
    v2& qdx, v2& qdy, v2& qdz, v2& qdwn,
    v2& wdx, v2& wdy) {
  v2 t = kA * wz;
  wdx = sx - t * wy;
  wdy = sy + t * wx;
  // thrust_w raw: a_xy = T2*(qw*(qy,-qx) + qz*(qx,qy)); az = T + cz - MG
  v2 m1 = qw * qy + qz * qx;
  ax = T2 * m1;
  v2 m2 = qz * qy - qw * qx;
  ay = T2 * m2;
  v2 s  = qx * qx + qy * qy;
  az = TmG - T2 * s;
  // qd' = 2*quat_derivative; qdwn is the POSITIVE sum (true qd'_w = -qdwn)
  qdx = qw * wx + qy * wz - qz * wy;
  qdy = qw * wy + qz * wx - qx * wz;
  qdz = qw * wz + qx * wy - qy * wx;
  qdwn = qx * wx + qy * wy + qz * wz;
}

// so3 log map for the pair, output-only. rsq reused as 1/|v| (saves a rcp).
__device__ __forceinline__ void logmap_pair(v2 qx, v2 qy, v2 qz, v2 qw,
                                            v2& rx, v2& ry, v2& rz) {
  v2 nv2 = qx * qx + qy * qy + qz * qz;
  v2 rs;
  rs.x = fast_rsq(fmaxf(nv2.x, 1e-20f));
  rs.y = fast_rsq(fmaxf(nv2.y, 1e-20f));
  v2 nv = nv2 * rs;                    // sqrt(nv2)
  v2 aw;
  aw.x = fabsf(qw.x); aw.y = fabsf(qw.y);
  v2 mn, mx;
  mn.x = fminf(nv.x, aw.x); mn.y = fminf(nv.y, aw.y);
  mx.x = fmaxf(nv.x, aw.x); mx.y = fmaxf(nv.y, aw.y);
  v2 rm;
  rm.x = fast_rcp(mx.x); rm.y = fast_rcp(mx.y);
  v2 t  = mn * rm;
  v2 t2 = t * t;
  v2 p = t2 * (-0.01172120f) + 0.05265332f;
  p = t2 * p - 0.11643287f;
  p = t2 * p + 0.19354346f;
  p = t2 * p - 0.33262347f;
  p = t2 * p + 0.99997726f;
  p = p * t;
  p.x = (nv.x > aw.x) ? (1.5707963268f - p.x) : p.x;
  p.y = (nv.y > aw.y) ? (1.5707963268f - p.y) : p.y;
  p.x = (qw.x < 0.0f) ? (3.1415926536f - p.x) : p.x;
  p.y = (qw.y < 0.0f) ? (3.1415926536f - p.y) : p.y;
  v2 k = (p + p) * rs;                 // ang/|v| = 2*atan * rsq(nv2)
  k.x = (nv.x < 1e-6f) ? 2.0f : k.x;
  k.y = (nv.y < 1e-6f) ? 2.0f : k.y;
  rx = k * qx; ry = k * qy; rz = k * qz;
}

__global__ __launch_bounds__(64) void quad_rk4_kernel(
    const float* __restrict__ x0,
    const float* __restrict__ u_seq,
    float* __restrict__ out) {
  const int b = blockIdx.x * 64 + threadIdx.x;   // 0..4095; pair = (b, b+4096)

  const float4* xvA = reinterpret_cast<const float4*>(x0) + (size_t)b * 3;
  const float4* xvB = reinterpret_cast<const float4*>(x0) + (size_t)(b + kHalf) * 3;
  float4 A0 = xvA[0], A1 = xvA[1], A2 = xvA[2];
  float4 B0 = xvB[0], B1 = xvB[1], B2 = xvB[2];

  v2 px = mk2(A0.x, B0.x), py = mk2(A0.y, B0.y), pz = mk2(A0.z, B0.z);
  v2 vx = mk2(A0.w, B0.w), vy = mk2(A1.x, B1.x), vz = mk2(A1.y, B1.y);
  v2 ox = mk2(A2.y, B2.y), oy = mk2(A2.z, B2.z), oz = mk2(A2.w, B2.w);

  float qxA, qyA, qzA, qwA, qxB, qyB, qzB, qwB;
  so3_to_quat_init(A1.z, A1.w, A2.x, qxA, qyA, qzA, qwA);
  so3_to_quat_init(B1.z, B1.w, B2.x, qxB, qyB, qzB, qwB);
  v2 qx = mk2(qxA, qxB), qy = mk2(qyA, qyB),
     qz = mk2(qzA, qzB), qw = mk2(qwA, qwB);

  const float4* uvA = reinterpret_cast<const float4*>(u_seq) + (size_t)b * kN;
  const float4* uvB = reinterpret_cast<const float4*>(u_seq) + (size_t)(b + kHalf) * kN;
  float4* ovA = reinterpret_cast<float4*>(out) + (size_t)b * kN * 3;
  float4* ovB = reinterpret_cast<float4*>(out) + (size_t)(b + kHalf) * kN * 3;

  // depth-2 prefetch (covers ~2 step-bodies ~2000 cyc >> ~900 cyc HBM)
  float4 uA0 = uvA[0], uA1 = uvA[1];
  float4 uB0 = uvB[0], uB1 = uvB[1];

#pragma unroll 4
  for (int t = 0; t < kN; ++t) {
    int tn = (t + 2 < kN) ? (t + 2) : (kN - 1);
    float4 nA = uvA[tn];
    float4 nB = uvB[tn];

    // ---- motor_to_phys (pair-packed) + per-step invariants ----
    v2 m0 = mk2(uA0.x, uB0.x), m1v = mk2(uA0.y, uB0.y),
       m2v = mk2(uA0.z, uB0.z), m3v = mk2(uA0.w, uB0.w);
    v2 w0 = m0 * m0, w1 = m1v * m1v, w2 = m2v * m2v, w3 = m3v * m3v;
    v2 s01 = w0 + w1, s23 = w2 + w3;
    v2 Traw = kKT * (s01 + s23);
    v2 T;
    T.x = fminf(Traw.x, kTmax); T.y = fminf(Traw.y, kTmax);  // >= 0 always
    v2 d1 = s23 - s01;
    v2 d2 = (w1 + w2) - (w0 + w3);
    v2 d3 = (w0 + w2) - (w1 + w3);
    v2 sx  = clamp2(kKTAJ * d1, kSxyLim);   // tau_x/Jx, clamp folded
    v2 sy  = clamp2(kKTAJ * d2, kSxyLim);
    v2 wdz = clamp2(kKCJ  * d3, kSzLim);    // stage-invariant (Jx==Jy)
    v2 T2 = T + T, TmG = T - kMG;
    v2 ozh = oz + kH  * wdz;                // omega_z at stages 2,3
    v2 ozf = oz + kDT * wdz;                // omega_z at stage 4 AND next

    // ---- stage 1 ----
    v2 a1x, a1y, a1z, qd1x, qd1y, qd1z, qd1w, wd1x, wd1y;
    dyn_pair(qx, qy, qz, qw, ox, oy, oz, T2, TmG, sx, sy,
             a1x, a1y, a1z, qd1x, qd1y, qd1z, qd1w, wd1x, wd1y);
    // accumulators (weights 1,2,2,1; Apos = a1+a2+a3)
    v2 Avx = a1x, Avy = a1y, Avz = a1z;
    v2 Apx = a1x, Apy = a1y, Apz = a1z;
    v2 Ox = wd1x, Oy = wd1y;
    v2 Qx = qd1x, Qy = qd1y, Qz = qd1z, Qw = qd1w;

    // ---- stage 2 ----
    v2 q2x = qx + kHq * qd1x, q2y = qy + kHq * qd1y,
       q2z = qz + kHq * qd1z, q2w = qw - kHq * qd1w;
    renorm4(q2x, q2y, q2z, q2w);
    v2 o2x = ox + kH * wd1x, o2y = oy + kH * wd1y;
    v2 a2x, a2y, a2z, qd2x, qd2y, qd2z, qd2w, wd2x, wd2y;
    dyn_pair(q2x, q2y, q2z, q2w, o2x, o2y, ozh, T2, TmG, sx, sy,
             a2x, a2y, a2z, qd2x, qd2y, qd2z, qd2w, wd2x, wd2y);
    Avx += 2.0f * a2x; Avy += 2.0f * a2y; Avz += 2.0f * a2z;
    Apx += a2x; Apy += a2y; Apz += a2z;
    Ox += 2.0f * wd2x; Oy += 2.0f * wd2y;
    Qx += 2.0f * qd2x; Qy += 2.0f * qd2y; Qz += 2.0f * qd2z; Qw += 2.0f * qd2w;

    // ---- stage 3 ----
    v2 q3x = qx + kHq * qd2x, q3y = qy + kHq * qd2y,
       q3z = qz + kHq * qd2z, q3w = qw - kHq * qd2w;
    renorm4(q3x, q3y, q3z, q3w);
    v2 o3x = ox + kH * wd2x, o3y = oy + kH * wd2y;
    v2 a3x, a3y, a3z, qd3x, qd3y, qd3z, qd3w, wd3x, wd3y;
    dyn_pair(q3x, q3y, q3z, q3w, o3x, o3y, ozh, T2, TmG, sx, sy,
             a3x, a3y, a3z, qd3x, qd3y, qd3z, qd3w, wd3x, wd3y);
    Avx += 2.0f * a3x; Avy += 2.0f * a3y; Avz += 2.0f * a3z;
    Apx += a3x; Apy += a3y; Apz += a3z;
    Ox += 2.0f * wd3x; Oy += 2.0f * wd3y;
    Qx += 2.0f * qd3x; Qy += 2.0f * qd3y; Qz += 2.0f * qd3z; Qw += 2.0f * qd3w;

    // ---- stage 4 (full step) ----
    v2 q4x = qx + kDTq * qd3x, q4y = qy + kDTq * qd3y,
       q4z = qz + kDTq * qd3z, q4w = qw - kDTq * qd3w;
    renorm4(q4x, q4y, q4z, q4w);
    v2 o4x = ox + kDT * wd3x, o4y = oy + kDT * wd3y;
    v2 a4x, a4y, a4z, qd4x, qd4y, qd4z, qd4w, wd4x, wd4y;
    dyn_pair(q4x, q4y, q4z, q4w, o4x, o4y, ozf, T2, TmG, sx, sy,
             a4x, a4y, a4z, qd4x, qd4y, qd4z, qd4w, wd4x, wd4y);
    Avx += a4x; Avy += a4y; Avz += a4z;
    Ox += wd4x; Oy += wd4y;
    Qx += qd4x; Qy += qd4y; Qz += qd4z; Qw += qd4w;

    // ---- RK4 combine (pos uses OLD vel; stage velocities eliminated) ----
    px += kDT * vx; px += kPC * Apx;
    py += kDT * vy; py += kPC * Apy;
    pz += kDT * vz; pz += kPC * Apz;
    vx += kVC * Avx; vy += kVC * Avy; vz += kVC * Avz;
    ox += kDT6 * Ox; oy += kDT6 * Oy; oz = ozf;
    qx += kDT6q * Qx; qy += kDT6q * Qy; qz += kDT6q * Qz; qw -= kDT6q * Qw;
    renorm4(qx, qy, qz, qw);

    // ---- output so3 log (off the loop-carried chain) + stores ----
    v2 rx, ry, rz;
    logmap_pair(qx, qy, qz, qw, rx, ry, rz);
    ovA[t * 3 + 0] = make_float4(px.x, py.x, pz.x, vx.x);
    ovA[t * 3 + 1] = make_float4(vy.x, vz.x, rx.x, ry.x);
    ovA[t * 3 + 2] = make_float4(rz.x, ox.x, oy.x, oz.x);
    ovB[t * 3 + 0] = make_float4(px.y, py.y, pz.y, vx.y);
    ovB[t * 3 + 1] = make_float4(vy.y, vz.y, rx.y, ry.y);
    ovB[t * 3 + 2] = make_float4(rz.y, ox.y, oy.y, oz.y);

    // rotate depth-2 prefetch (renamed away by unroll-4)
    uA0 = uA1; uA1 = nA;
    uB0 = uB1; uB1 = nB;
  }
}

extern "C" void kernel_launch(void* const* d_in, const int* in_sizes, int n_in,
                              void* d_out, int out_size, void* d_ws, size_t ws_size,
                              hipStream_t stream) {
  const float* x0    = (const float*)d_in[0];   // (8192, 12)
  const float* u_seq = (const float*)d_in[1];   // (8192, 256, 4)
  float*       out   = (float*)d_out;           // (8192, 256, 12)
  (void)in_sizes; (void)n_in; (void)out_size; (void)d_ws; (void)ws_size;

  dim3 block(64);
  dim3 grid(kHalf / 64);  // 4096 threads = 64 waves, 2 trajectories/thread
  quad_rk4_kernel<<<grid, block, 0, stream>>>(x0, u_seq, out);
}

// Round 3
// 233.829 us; speedup vs baseline: 1.2602x; 1.2602x over previous
//
#include <hip/hip_runtime.h>
#include <math.h>

// PhysQuadModel: batched RK4 rollout of quadrotor dynamics.
// R7: component-packed (xy) v_pk + algebra: 125us rocprof (PROVEN BASE).
// R8: trajectory-pair packing REGRESSED (203us): wall = per-WAVE serial
//     stream latency; packing 2 trajectories/wave made the stream 1.62x
//     longer. Wave count is irrelevant (1 wave/SIMD everywhere).
// R9 (this): producer/consumer WAVE SPLIT. accel/vel/pos/logmap/stores never
//   feed back into dyn (dyn needs only q, omega, tau) -> move them to a
//   partner wave. Producer keeps only the q/omega chain (~135 inst/step vs
//   R7's ~215) and ships stage quats + omega via LDS (5x ds_write_b128,
//   double-buffered, one __syncthreads/step). Consumer (~105 inst/step,
//   hides under producer): own u load (L1 hit) for T, 4 stage accels,
//   p/v integration, logmap, stores. Arithmetic bit-identical to R7.

namespace {
constexpr int   kB    = 8192;
constexpr int   kN    = 256;
constexpr float kDT   = 0.01f;
constexpr float kMG   = 0.033f * 9.81f;        // M*G
constexpr float kTmax = 1.9f * 0.033f * 9.81f; // 0.6150870
constexpr float kKT   = 3.8e-08f;
constexpr float kKC   = 3.8e-11f;
constexpr float kKTA  = kKT * 0.04f;           // KT*ARM
constexpr float kInvM = 1.0f / 0.033f;
constexpr float kJx   = 1.4e-05f, kJz = 2.17e-05f;
constexpr float kInvJx = 1.0f / 1.4e-05f;
constexpr float kInvJz = 1.0f / 2.17e-05f;
constexpr float kA    = (kJz - kJx) * kInvJx;  // 0.55 (Jx==Jy)
constexpr float kTq0  = 0.009f, kTq1 = 0.009f, kTq2 = 0.002f;
constexpr float kH    = 0.005f;                // 0.5*dt   (omega euler)
constexpr float kHq   = 0.0025f;               // 0.5*dt*0.5 (qd' = 2*qd)
constexpr float kDTq  = 0.005f;                // dt*0.5   (stage-4 quat)
constexpr float kDT6  = 0.0016666667f;         // dt/6
constexpr float kDT6q = 0.5f * kDT6;           // dt/12
constexpr float kVC   = kDT6 * kInvM;          // raw accel -> vel
constexpr float kPC   = kDT6 * kDT * kInvM;    // raw accel -> pos
}

typedef float v2 __attribute__((ext_vector_type(2)));

__device__ __forceinline__ v2 mk2(float a, float b) { v2 r; r.x = a; r.y = b; return r; }
__device__ __forceinline__ float fast_rcp(float x) { return __builtin_amdgcn_rcpf(x); }
__device__ __forceinline__ float fast_rsq(float x) { return __builtin_amdgcn_rsqf(x); }

// atan2 for y >= 0, result in [0, pi]. Minimax atan poly on [0,1], err ~1e-5.
__device__ __forceinline__ float atan2_pos(float y, float x) {
  float axx = fabsf(x);
  float mn  = fminf(y, axx);
  float mx  = fmaxf(y, axx);
  float t   = mn * fast_rcp(mx);
  float t2  = t * t;
  float p = fmaf(t2, -0.01172120f, 0.05265332f);
  p = fmaf(t2, p, -0.11643287f);
  p = fmaf(t2, p, 0.19354346f);
  p = fmaf(t2, p, -0.33262347f);
  p = fmaf(t2, p, 0.99997726f);
  p *= t;
  p = (y > axx) ? (1.5707963268f - p) : p;
  p = (x < 0.0f) ? (3.1415926536f - p) : p;
  return p;
}

// accurate, used ONCE per trajectory at init (both waves)
__device__ __forceinline__ void so3_to_quat_init(float rx, float ry, float rz,
                                                 float& qx, float& qy, float& qz, float& qw) {
  float theta = sqrtf(rx * rx + ry * ry + rz * rz);
  float half  = 0.5f * theta;
  float s     = sinf(half);
  float c     = cosf(half);
  float k     = s / (theta + 1e-8f);
  bool  small = theta < 1e-6f;
  k  = small ? 0.5f : k;
  qw = small ? 1.0f : c;
  qx = k * rx; qy = k * ry; qz = k * rz;
}

// log map, output-only path (consumer wave)
__device__ __forceinline__ void quat_to_so3_fast(float qx, float qy, float qz, float qw,
                                                 float& rx, float& ry, float& rz) {
  float nv2 = qx * qx + qy * qy + qz * qz;
  float nv  = nv2 * fast_rsq(fmaxf(nv2, 1e-20f));   // sqrt(nv2), safe at 0
  float wc  = fminf(fmaxf(qw, -0.999999f), 0.999999f);
  float ang = 2.0f * atan2_pos(nv, wc);
  float k   = ang * fast_rcp(nv + 1e-6f);
  k = (nv < 1e-6f) ? 2.0f : k;
  rx = k * qx; ry = k * qy; rz = k * qz;
}

// Newton renorm from y0=1 (|q|^2 = 1+eps): no transcendental (as R7).
__device__ __forceinline__ void renorm(v2& a, v2& b) {
  v2 s = a * a + b * b;
  float c = 1.5f - 0.5f * (s.x + s.y);
  a *= c; b *= c;
}

// producer dyn: q/omega derivatives ONLY (accel stripped out; it is computed
// by the consumer wave from the stage quats). Same formulas as R7's dyn_pk.
__device__ __forceinline__ void dyn_q(
    v2 q_xy, v2 q_zw, v2 w_xy, float wz, v2 s_xy,
    v2& qd_xy, v2& qd_zw, v2& wd_xy) {
  float qx = q_xy.x, qy = q_xy.y, qz = q_zw.x, qw = q_zw.y;
  v2 aq = mk2(qy, -qx);
  v2 pw = mk2(-w_xy.y, w_xy.x);
  wd_xy = s_xy + (kA * wz) * pw;
  qd_xy = qw * w_xy + wz * aq + qz * pw;
  qd_zw = wz * mk2(qw, -qz) + qx * mk2(w_xy.y, -w_xy.x) - qy * w_xy;
}

// consumer accel from a stage quat (raw, 1/M deferred). Same as R7's lines.
__device__ __forceinline__ void acc_q(float qx, float qy, float qz, float qw,
                                      float T2, float TmG,
                                      v2& a_xy, float& az) {
  v2 t_xy = T2 * mk2(qy, -qx);
  a_xy = qw * t_xy + qz * mk2(-t_xy.y, t_xy.x);
  az   = TmG - T2 * (qx * qx + qy * qy);
}

__global__ __launch_bounds__(128) void quad_rk4_kernel(
    const float* __restrict__ x0,
    const float* __restrict__ u_seq,
    float* __restrict__ out) {
  // [slot][field 0..4][lane] float4, contiguous per field -> ds_*_b128 fast path
  __shared__ float4 lds4[2 * 5 * 64];

  const int lane = threadIdx.x & 63;
  const int wid  = threadIdx.x >> 6;
  const int b    = blockIdx.x * 64 + lane;

  const float4* xv = reinterpret_cast<const float4*>(x0) + (size_t)b * 3;
  float4 s0 = xv[0], s1 = xv[1], s2 = xv[2];
  const float4* uv = reinterpret_cast<const float4*>(u_seq) + (size_t)b * kN;

  if (wid == 0) {
    // ================= PRODUCER: q / omega chain =================
    v2 o_xy = mk2(s2.y, s2.z);  float oz = s2.w;
    float qx0, qy0, qz0, qw0;
    so3_to_quat_init(s1.z, s1.w, s2.x, qx0, qy0, qz0, qw0);
    v2 q_xy = mk2(qx0, qy0), q_zw = mk2(qz0, qw0);

    float4 u0 = uv[0], u1 = uv[1];

#pragma unroll 2
    for (int t = 0; t < kN; ++t) {
      int tn = (t + 2 < kN) ? (t + 2) : (kN - 1);
      float4 un = uv[tn];
      float4 u = u0;

      // tau part of motor_to_phys (bit-identical to R7's sequence)
      float w20 = u.x * u.x, w21 = u.y * u.y, w22 = u.z * u.z, w23 = u.w * u.w;
      float sa = w20 + w21, sb = w22 + w23;
      float tq1 = kKTA * (sb - sa);
      float tq2 = kKTA * ((w21 + w22) - (w20 + w23));
      float tq3 = kKC  * ((w20 + w22) - (w21 + w23));
      tq1 = __builtin_amdgcn_fmed3f(tq1, -kTq0, kTq0);
      tq2 = __builtin_amdgcn_fmed3f(tq2, -kTq1, kTq1);
      tq3 = __builtin_amdgcn_fmed3f(tq3, -kTq2, kTq2);
      v2    s_xy = mk2(tq1 * kInvJx, tq2 * kInvJx);
      float wdz  = tq3 * kInvJz;          // stage-invariant (Jx==Jy)
      float ozh  = fmaf(kH,  wdz, oz);
      float ozf  = fmaf(kDT, wdz, oz);

      // stage 1
      v2 qd1_xy, qd1_zw, wd1;
      dyn_q(q_xy, q_zw, o_xy, oz, s_xy, qd1_xy, qd1_zw, wd1);
      // stage 2
      v2 q2_xy = q_xy + kHq * qd1_xy, q2_zw = q_zw + kHq * qd1_zw;
      renorm(q2_xy, q2_zw);
      v2 o2 = o_xy + kH * wd1;
      v2 qd2_xy, qd2_zw, wd2;
      dyn_q(q2_xy, q2_zw, o2, ozh, s_xy, qd2_xy, qd2_zw, wd2);
      // stage 3
      v2 q3_xy = q_xy + kHq * qd2_xy, q3_zw = q_zw + kHq * qd2_zw;
      renorm(q3_xy, q3_zw);
      v2 o3 = o_xy + kH * wd2;
      v2 qd3_xy, qd3_zw, wd3;
      dyn_q(q3_xy, q3_zw, o3, ozh, s_xy, qd3_xy, qd3_zw, wd3);
      // stage 4
      v2 q4_xy = q_xy + kDTq * qd3_xy, q4_zw = q_zw + kDTq * qd3_zw;
      renorm(q4_xy, q4_zw);
      v2 o4 = o_xy + kDT * wd3;
      v2 qd4_xy, qd4_zw, wd4;
      dyn_q(q4_xy, q4_zw, o4, ozf, s_xy, qd4_xy, qd4_zw, wd4);

      // combine omega / quat (R7 trees)
      v2 w23v = wd2 + wd3;
      o_xy = o_xy + kDT6 * ((wd1 + w23v) + (w23v + wd4));
      oz = ozf;
      v2 qxy23 = qd2_xy + qd3_xy;
      q_xy = q_xy + kDT6q * ((qd1_xy + qxy23) + (qxy23 + qd4_xy));
      v2 qzw23 = qd2_zw + qd3_zw;
      q_zw = q_zw + kDT6q * ((qd1_zw + qzw23) + (qzw23 + qd4_zw));
      renorm(q_xy, q_zw);

      // send stage quats + new quat + new omega
      float4* dst = &lds4[(t & 1) * 320 + lane];
      dst[0 * 64] = make_float4(q2_xy.x, q2_xy.y, q2_zw.x, q2_zw.y);
      dst[1 * 64] = make_float4(q3_xy.x, q3_xy.y, q3_zw.x, q3_zw.y);
      dst[2 * 64] = make_float4(q4_xy.x, q4_xy.y, q4_zw.x, q4_zw.y);
      dst[3 * 64] = make_float4(q_xy.x, q_xy.y, q_zw.x, q_zw.y);
      dst[4 * 64] = make_float4(o_xy.x, o_xy.y, oz, 0.0f);
      __syncthreads();

      u0 = u1; u1 = un;
    }
  } else {
    // ================= CONSUMER: accel / p / v / logmap / stores =========
    v2 p_xy = mk2(s0.x, s0.y);  float pz = s0.z;
    v2 v_xy = mk2(s0.w, s1.x);  float vz = s1.y;
    // q at start of step t (= q_new of t-1); init from x0
    float qpx, qpy, qpz, qpw;
    so3_to_quat_init(s1.z, s1.w, s2.x, qpx, qpy, qpz, qpw);

    float4* ov = reinterpret_cast<float4*>(out) + (size_t)b * kN * 3;
    float4 u0 = uv[0], u1 = uv[1];

#pragma unroll 2
    for (int t = 0; t < kN; ++t) {
      int tn = (t + 2 < kN) ? (t + 2) : (kN - 1);
      float4 un = uv[tn];
      float4 u = u0;

      // thrust part of motor_to_phys (bit-identical to R7)
      float w20 = u.x * u.x, w21 = u.y * u.y, w22 = u.z * u.z, w23 = u.w * u.w;
      float T  = fminf(kKT * ((w20 + w21) + (w22 + w23)), kTmax);
      float T2 = T + T, TmG = T - kMG;

      __syncthreads();
      const float4* src = &lds4[(t & 1) * 320 + lane];
      float4 Q2 = src[0 * 64];
      float4 Q3 = src[1 * 64];
      float4 Q4 = src[2 * 64];
      float4 QN = src[3 * 64];
      float4 OM = src[4 * 64];

      v2 a1, a2, a3, a4; float az1, az2, az3, az4;
      acc_q(qpx, qpy, qpz, qpw, T2, TmG, a1, az1);
      acc_q(Q2.x, Q2.y, Q2.z, Q2.w, T2, TmG, a2, az2);
      acc_q(Q3.x, Q3.y, Q3.z, Q3.w, T2, TmG, a3, az3);
      acc_q(Q4.x, Q4.y, Q4.z, Q4.w, T2, TmG, a4, az4);

      // RK4 combine (pos uses OLD vel; stage velocities eliminated — R7)
      v2 t23 = a2 + a3;
      v2 Apos = a1 + t23;
      v2 Avel = Apos + t23 + a4;
      p_xy = p_xy + kDT * v_xy;  p_xy = p_xy + kPC * Apos;
      float az23 = az2 + az3;
      float Aposz = az1 + az23;
      float Avelz = Aposz + az23 + az4;
      pz = fmaf(kDT, vz, pz);  pz = fmaf(kPC, Aposz, pz);
      v_xy = v_xy + kVC * Avel;
      vz   = fmaf(kVC, Avelz, vz);

      // output so3 log of the NEW quat + stores
      float rx, ry, rz;
      quat_to_so3_fast(QN.x, QN.y, QN.z, QN.w, rx, ry, rz);
      ov[t * 3 + 0] = make_float4(p_xy.x, p_xy.y, pz, v_xy.x);
      ov[t * 3 + 1] = make_float4(v_xy.y, vz, rx, ry);
      ov[t * 3 + 2] = make_float4(rz, OM.x, OM.y, OM.z);

      qpx = QN.x; qpy = QN.y; qpz = QN.z; qpw = QN.w;
      u0 = u1; u1 = un;
    }
  }
}

extern "C" void kernel_launch(void* const* d_in, const int* in_sizes, int n_in,
                              void* d_out, int out_size, void* d_ws, size_t ws_size,
                              hipStream_t stream) {
  const float* x0    = (const float*)d_in[0];   // (8192, 12)
  const float* u_seq = (const float*)d_in[1];   // (8192, 256, 4)
  float*       out   = (float*)d_out;           // (8192, 256, 12)
  (void)in_sizes; (void)n_in; (void)out_size; (void)d_ws; (void)ws_size;

  dim3 block(128);            // wave0 = producer, wave1 = consumer
  dim3 grid(kB / 64);         // 128 blocks, 64 trajectories each
  quad_rk4_kernel<<<grid, block, 0, stream>>>(x0, u_seq, out);
}

// Round 5
// 229.871 us; speedup vs baseline: 1.2819x; 1.0172x over previous
//
#include <hip/hip_runtime.h>
#include <math.h>

// PhysQuadModel: batched RK4 rollout of quadrotor dynamics.
// One thread per trajectory (B=8192), 256 sequential RK4 steps, 128 waves =
// 1 wave/SIMD: wall time = per-wave serial stream at ~5.5 cyc/inst (stable
// cadence measured across R6/R7/R8; NOT fillable by extra in-wave ILP).
// R7: xy-pk + algebra (wdz hoist, Newton renorm, stage-vel elimination): 125us.
// R8: traj-pair packing REGRESSED (203us): wall = per-WAVE stream length.
// R9: producer/consumer wave split REGRESSED (140us): per-step barrier costs
//     ~540 cyc (lgkm drain + handshake + LDS latency), eating the split gain.
// R10 (this): R7 base, pure instruction shave (~-36 inst/step):
//   - drop 3 stage renorms (qdot perp q => stage norm err ~5e-5; output shift
//     ~1e-3 << absmax outlier 0.31). Keep loop-carried renorm.
//   - torque clamps pre-scaled by 1/J -> single v_med3 each.
//   - logmap: rs-reuse for 1/nv (exact), no qw clamp, no small-nv select.
//   - T2/TmG fold.
// (R10a: fixed w23 name collision — motor scalar vs combine temp.)

namespace {
constexpr int   kB    = 8192;
constexpr int   kN    = 256;
constexpr float kDT   = 0.01f;
constexpr float kMG   = 0.033f * 9.81f;        // M*G
constexpr float kKT   = 3.8e-08f;
constexpr float kKT2  = 2.0f * kKT;
constexpr float kTmax2= 2.0f * 1.9f * 0.033f * 9.81f; // 2*Tmax
constexpr float kKC   = 3.8e-11f;
constexpr float kKTA  = kKT * 0.04f;           // KT*ARM
constexpr float kInvM = 1.0f / 0.033f;
constexpr float kJx   = 1.4e-05f, kJz = 2.17e-05f;
constexpr float kInvJx = 1.0f / 1.4e-05f;
constexpr float kInvJz = 1.0f / 2.17e-05f;
constexpr float kA    = (kJz - kJx) * kInvJx;  // 0.55 (Jx==Jy)
constexpr float kKTAJ   = kKTA * kInvJx;       // torque->omega_dot, pre-clamp
constexpr float kKCJ    = kKC * kInvJz;
constexpr float kSxyLim = 0.009f * kInvJx;
constexpr float kSzLim  = 0.002f * kInvJz;
constexpr float kH    = 0.005f;                // 0.5*dt   (omega euler)
constexpr float kHq   = 0.0025f;               // 0.5*dt*0.5 (qd' = 2*qd)
constexpr float kDTq  = 0.005f;                // dt*0.5   (stage-4 quat)
constexpr float kDT6  = 0.0016666667f;         // dt/6
constexpr float kDT6q = 0.5f * kDT6;           // dt/12
constexpr float kVC   = kDT6 * kInvM;          // raw accel -> vel
constexpr float kPC   = kDT6 * kDT * kInvM;    // raw accel -> pos
constexpr int   kPF   = 8;                     // prefetch pipeline depth
}

typedef float v2 __attribute__((ext_vector_type(2)));

__device__ __forceinline__ v2 mk2(float a, float b) { v2 r; r.x = a; r.y = b; return r; }
__device__ __forceinline__ float fast_rcp(float x) { return __builtin_amdgcn_rcpf(x); }
__device__ __forceinline__ float fast_rsq(float x) { return __builtin_amdgcn_rsqf(x); }

// accurate version used ONCE at init (outside the hot loop)
__device__ __forceinline__ void so3_to_quat_init(float rx, float ry, float rz,
                                                 float& qx, float& qy, float& qz, float& qw) {
  float theta = sqrtf(rx * rx + ry * ry + rz * rz);
  float half  = 0.5f * theta;
  float s     = sinf(half);
  float c     = cosf(half);
  float k     = s / (theta + 1e-8f);
  bool  small = theta < 1e-6f;
  k  = small ? 0.5f : k;
  qw = small ? 1.0f : c;
  qx = k * rx; qy = k * ry; qz = k * rz;
}

// log map, output-only path. rs = rsqrt(nv2) reused as 1/nv (exact); k -> 2
// analytically as nv -> 0 so no small-select; qw clamp dropped (effect <=1e-6).
__device__ __forceinline__ void quat_to_so3_fast(float qx, float qy, float qz, float qw,
                                                 float& rx, float& ry, float& rz) {
  float nv2 = qx * qx + qy * qy + qz * qz;
  float rs  = fast_rsq(fmaxf(nv2, 1e-20f));
  float nv  = nv2 * rs;                        // sqrt(nv2)
  float aw  = fabsf(qw);
  float mn  = fminf(nv, aw);
  float mx  = fmaxf(nv, aw);
  float t   = mn * fast_rcp(mx);
  float t2  = t * t;
  float p = fmaf(t2, -0.01172120f, 0.05265332f);
  p = fmaf(t2, p, -0.11643287f);
  p = fmaf(t2, p, 0.19354346f);
  p = fmaf(t2, p, -0.33262347f);
  p = fmaf(t2, p, 0.99997726f);
  p *= t;
  p = (nv > aw) ? (1.5707963268f - p) : p;
  p = (qw < 0.0f) ? (3.1415926536f - p) : p;
  float k = (p + p) * rs;                      // 2*atan * (1/nv)
  rx = k * qx; ry = k * qy; rz = k * qz;
}

// Newton renorm from y0=1 (|q|^2 = 1+eps): no transcendental.
__device__ __forceinline__ void renorm(v2& a, v2& b) {
  v2 s = a * a + b * b;
  float c = 1.5f - 0.5f * (s.x + s.y);
  a *= c; b *= c;
}

// dyn core with pre-clamped tau/J; raw accel (1/M deferred); qd' = 2*qd.
__device__ __forceinline__ void dyn_pk(
    v2 q_xy, v2 q_zw, v2 w_xy, float wz,
    float T2, float TmG, v2 s_xy,
    v2& a_xy, float& az, v2& qd_xy, v2& qd_zw, v2& wd_xy) {
  float qx = q_xy.x, qy = q_xy.y, qz = q_zw.x, qw = q_zw.y;
  v2 aq = mk2(qy, -qx);            // shared by thrust + qd
  v2 pw = mk2(-w_xy.y, w_xy.x);    // shared by wd + qd
  v2 t_xy = T2 * aq;
  a_xy = qw * t_xy + qz * mk2(-t_xy.y, t_xy.x);
  az   = TmG - T2 * (qx * qx + qy * qy);       // T + cz - MG
  wd_xy = s_xy + (kA * wz) * pw;
  qd_xy = qw * w_xy + wz * aq + qz * pw;
  qd_zw = wz * mk2(qw, -qz) + qx * mk2(w_xy.y, -w_xy.x) - qy * w_xy;
}

__global__ __launch_bounds__(64) void quad_rk4_kernel(
    const float* __restrict__ x0,
    const float* __restrict__ u_seq,
    float* __restrict__ out) {
  const int b = blockIdx.x * 64 + threadIdx.x;
  if (b >= kB) return;

  const float4* xv = reinterpret_cast<const float4*>(x0) + (size_t)b * 3;
  float4 s0 = xv[0], s1 = xv[1], s2 = xv[2];
  v2    p_xy = mk2(s0.x, s0.y);  float pz = s0.z;
  v2    v_xy = mk2(s0.w, s1.x);  float vz = s1.y;
  v2    o_xy = mk2(s2.y, s2.z);  float oz = s2.w;

  float qx0, qy0, qz0, qw0;
  so3_to_quat_init(s1.z, s1.w, s2.x, qx0, qy0, qz0, qw0);
  v2 q_xy = mk2(qx0, qy0), q_zw = mk2(qz0, qw0);   // loop-carried unit quat

  const float4* uv = reinterpret_cast<const float4*>(u_seq) + (size_t)b * kN;
  float4*       ov = reinterpret_cast<float4*>(out) + (size_t)b * kN * 3;

  // depth-8 software-prefetch pipeline
  float4 u0 = uv[0], u1 = uv[1], u2 = uv[2], u3 = uv[3],
         u4 = uv[4], u5 = uv[5], u6 = uv[6], u7 = uv[7];

#pragma unroll 8
  for (int t = 0; t < kN; ++t) {
    float4 u_new = uv[(t + kPF < kN) ? (t + kPF) : (kN - 1)];
    float4 u = u0;

    // ---- motor_to_phys + per-step invariants ----
    float m20 = u.x * u.x, m21 = u.y * u.y, m22 = u.z * u.z, m23 = u.w * u.w;
    float sa = m20 + m21, sb = m22 + m23;
    float T2  = fminf(kKT2 * (sa + sb), kTmax2);          // 2*T, >=0 always
    float TmG = fmaf(0.5f, T2, -kMG);
    float tq1 = kKTAJ * (sb - sa);
    float tq2 = kKTAJ * ((m21 + m22) - (m20 + m23));
    float tq3 = kKCJ  * ((m20 + m22) - (m21 + m23));
    v2    s_xy = mk2(__builtin_amdgcn_fmed3f(tq1, -kSxyLim, kSxyLim),
                     __builtin_amdgcn_fmed3f(tq2, -kSxyLim, kSxyLim));
    float wdz  = __builtin_amdgcn_fmed3f(tq3, -kSzLim, kSzLim);  // stage-inv
    float ozh  = fmaf(kH,  wdz, oz);   // omega_z at stages 2,3
    float ozf  = fmaf(kDT, wdz, oz);   // omega_z at stage 4 AND next step

    // ---- stage 1 ----
    float a1z; v2 a1, qd1_xy, qd1_zw, wd1;
    dyn_pk(q_xy, q_zw, o_xy, oz, T2, TmG, s_xy, a1, a1z, qd1_xy, qd1_zw, wd1);

    // ---- stage 2 (stage renorm dropped: norm err ~5e-5, see header) ----
    v2 q2_xy = q_xy + kHq * qd1_xy, q2_zw = q_zw + kHq * qd1_zw;
    v2 o2 = o_xy + kH * wd1;
    float a2z; v2 a2, qd2_xy, qd2_zw, wd2;
    dyn_pk(q2_xy, q2_zw, o2, ozh, T2, TmG, s_xy, a2, a2z, qd2_xy, qd2_zw, wd2);

    // ---- stage 3 ----
    v2 q3_xy = q_xy + kHq * qd2_xy, q3_zw = q_zw + kHq * qd2_zw;
    v2 o3 = o_xy + kH * wd2;
    float a3z; v2 a3, qd3_xy, qd3_zw, wd3;
    dyn_pk(q3_xy, q3_zw, o3, ozh, T2, TmG, s_xy, a3, a3z, qd3_xy, qd3_zw, wd3);

    // ---- stage 4 (full step) ----
    v2 q4_xy = q_xy + kDTq * qd3_xy, q4_zw = q_zw + kDTq * qd3_zw;
    v2 o4 = o_xy + kDT * wd3;
    float a4z; v2 a4, qd4_xy, qd4_zw, wd4;
    dyn_pk(q4_xy, q4_zw, o4, ozf, T2, TmG, s_xy, a4, a4z, qd4_xy, qd4_zw, wd4);

    // ---- RK4 combine (pos uses OLD vel; stage velocities eliminated) ----
    v2 t23 = a2 + a3;
    v2 Apos = a1 + t23;
    v2 Avel = Apos + t23 + a4;        // a1 + 2a2 + 2a3 + a4
    p_xy = p_xy + kDT * v_xy;  p_xy = p_xy + kPC * Apos;
    float az23 = a2z + a3z;
    float Aposz = a1z + az23;
    float Avelz = Aposz + az23 + a4z;
    pz = fmaf(kDT, vz, pz);  pz = fmaf(kPC, Aposz, pz);
    v_xy = v_xy + kVC * Avel;
    vz   = fmaf(kVC, Avelz, vz);
    v2 wdsum23 = wd2 + wd3;
    o_xy = o_xy + kDT6 * ((wd1 + wdsum23) + (wdsum23 + wd4));
    oz = ozf;
    v2 qxy23 = qd2_xy + qd3_xy;
    q_xy = q_xy + kDT6q * ((qd1_xy + qxy23) + (qxy23 + qd4_xy));
    v2 qzw23 = qd2_zw + qd3_zw;
    q_zw = q_zw + kDT6q * ((qd1_zw + qzw23) + (qzw23 + qd4_zw));
    renorm(q_xy, q_zw);               // loop-carried renorm kept

    // ---- output so3 (off the loop-carried chain) + stores ----
    float rx, ry, rz;
    quat_to_so3_fast(q_xy.x, q_xy.y, q_zw.x, q_zw.y, rx, ry, rz);
    ov[t * 3 + 0] = make_float4(p_xy.x, p_xy.y, pz, v_xy.x);
    ov[t * 3 + 1] = make_float4(v_xy.y, vz, rx, ry);
    ov[t * 3 + 2] = make_float4(rz, o_xy.x, o_xy.y, oz);

    // rotate the 8-deep prefetch pipeline (free renames after unroll-8)
    u0 = u1; u1 = u2; u2 = u3; u3 = u4; u4 = u5; u5 = u6; u6 = u7; u7 = u_new;
  }
}

extern "C" void kernel_launch(void* const* d_in, const int* in_sizes, int n_in,
                              void* d_out, int out_size, void* d_ws, size_t ws_size,
                              hipStream_t stream) {
  const float* x0    = (const float*)d_in[0];   // (8192, 12)
  const float* u_seq = (const float*)d_in[1];   // (8192, 256, 4)
  float*       out   = (float*)d_out;           // (8192, 256, 12)
  (void)in_sizes; (void)n_in; (void)out_size; (void)d_ws; (void)ws_size;

  dim3 block(64);
  dim3 grid(kB / 64);   // 128 waves, 1 thread per trajectory, 1 wave/SIMD
  quad_rk4_kernel<<<grid, block, 0, stream>>>(x0, u_seq, out);
}

// Round 6
// 207.957 us; speedup vs baseline: 1.4170x; 1.1054x over previous
//
#include <hip/hip_runtime.h>
#include <math.h>

// PhysQuadModel: batched RK4 rollout of quadrotor dynamics.
// Ladder (rocprof): R6 192 | R7 125 (single-wave floor) | R8 203 (pair-pack:
//   wall = per-wave stream length) | R9 140 (wave split, 537 cyc/step sync)
//   | R10 136 (further shave REGRESSED: lone-wave cadence ~5.5 cyc/inst is
//   scheduling-sensitive, not purely inst-count-proportional).
// R11 (this): R9's producer/consumer split with K=4 STEP BATCHING per
//   barrier. R9 measured producer-alone ~776 cyc/step and sync ~537/step;
//   batching amortizes sync to ~134/step -> ~910 cyc/step ~ 97us predicted.
//   Producer math BIT-IDENTICAL to R9 (passed, absmax 0.3125). LDS double
//   buffer 2 slots x 4 steps x 5 fields x 64 lanes x float4 = 40KB, one
//   __syncthreads per 4 steps on both sides (64 barriers each).

namespace {
constexpr int   kB    = 8192;
constexpr int   kN    = 256;
constexpr float kDT   = 0.01f;
constexpr float kMG   = 0.033f * 9.81f;        // M*G
constexpr float kTmax = 1.9f * 0.033f * 9.81f; // 0.6150870
constexpr float kKT   = 3.8e-08f;
constexpr float kKC   = 3.8e-11f;
constexpr float kKTA  = kKT * 0.04f;           // KT*ARM
constexpr float kInvM = 1.0f / 0.033f;
constexpr float kJx   = 1.4e-05f, kJz = 2.17e-05f;
constexpr float kInvJx = 1.0f / 1.4e-05f;
constexpr float kInvJz = 1.0f / 2.17e-05f;
constexpr float kA    = (kJz - kJx) * kInvJx;  // 0.55 (Jx==Jy)
constexpr float kTq0  = 0.009f, kTq1 = 0.009f, kTq2 = 0.002f;
constexpr float kH    = 0.005f;                // 0.5*dt   (omega euler)
constexpr float kHq   = 0.0025f;               // 0.5*dt*0.5 (qd' = 2*qd)
constexpr float kDTq  = 0.005f;                // dt*0.5   (stage-4 quat)
constexpr float kDT6  = 0.0016666667f;         // dt/6
constexpr float kDT6q = 0.5f * kDT6;           // dt/12
constexpr float kVC   = kDT6 * kInvM;          // raw accel -> vel
constexpr float kPC   = kDT6 * kDT * kInvM;    // raw accel -> pos
}

typedef float v2 __attribute__((ext_vector_type(2)));

__device__ __forceinline__ v2 mk2(float a, float b) { v2 r; r.x = a; r.y = b; return r; }
__device__ __forceinline__ float fast_rcp(float x) { return __builtin_amdgcn_rcpf(x); }
__device__ __forceinline__ float fast_rsq(float x) { return __builtin_amdgcn_rsqf(x); }

// atan2 for y >= 0, result in [0, pi]. Minimax atan poly on [0,1], err ~1e-5.
__device__ __forceinline__ float atan2_pos(float y, float x) {
  float axx = fabsf(x);
  float mn  = fminf(y, axx);
  float mx  = fmaxf(y, axx);
  float t   = mn * fast_rcp(mx);
  float t2  = t * t;
  float p = fmaf(t2, -0.01172120f, 0.05265332f);
  p = fmaf(t2, p, -0.11643287f);
  p = fmaf(t2, p, 0.19354346f);
  p = fmaf(t2, p, -0.33262347f);
  p = fmaf(t2, p, 0.99997726f);
  p *= t;
  p = (y > axx) ? (1.5707963268f - p) : p;
  p = (x < 0.0f) ? (3.1415926536f - p) : p;
  return p;
}

// accurate, used ONCE per trajectory at init (both waves)
__device__ __forceinline__ void so3_to_quat_init(float rx, float ry, float rz,
                                                 float& qx, float& qy, float& qz, float& qw) {
  float theta = sqrtf(rx * rx + ry * ry + rz * rz);
  float half  = 0.5f * theta;
  float s     = sinf(half);
  float c     = cosf(half);
  float k     = s / (theta + 1e-8f);
  bool  small = theta < 1e-6f;
  k  = small ? 0.5f : k;
  qw = small ? 1.0f : c;
  qx = k * rx; qy = k * ry; qz = k * rz;
}

// log map, output-only path (consumer wave) — R9 version, bit-identical
__device__ __forceinline__ void quat_to_so3_fast(float qx, float qy, float qz, float qw,
                                                 float& rx, float& ry, float& rz) {
  float nv2 = qx * qx + qy * qy + qz * qz;
  float nv  = nv2 * fast_rsq(fmaxf(nv2, 1e-20f));   // sqrt(nv2), safe at 0
  float wc  = fminf(fmaxf(qw, -0.999999f), 0.999999f);
  float ang = 2.0f * atan2_pos(nv, wc);
  float k   = ang * fast_rcp(nv + 1e-6f);
  k = (nv < 1e-6f) ? 2.0f : k;
  rx = k * qx; ry = k * qy; rz = k * qz;
}

// Newton renorm from y0=1 (|q|^2 = 1+eps): no transcendental.
__device__ __forceinline__ void renorm(v2& a, v2& b) {
  v2 s = a * a + b * b;
  float c = 1.5f - 0.5f * (s.x + s.y);
  a *= c; b *= c;
}

// producer dyn: q/omega derivatives ONLY (accel computed by consumer wave).
__device__ __forceinline__ void dyn_q(
    v2 q_xy, v2 q_zw, v2 w_xy, float wz, v2 s_xy,
    v2& qd_xy, v2& qd_zw, v2& wd_xy) {
  float qx = q_xy.x, qy = q_xy.y, qz = q_zw.x, qw = q_zw.y;
  v2 aq = mk2(qy, -qx);
  v2 pw = mk2(-w_xy.y, w_xy.x);
  wd_xy = s_xy + (kA * wz) * pw;
  qd_xy = qw * w_xy + wz * aq + qz * pw;
  qd_zw = wz * mk2(qw, -qz) + qx * mk2(w_xy.y, -w_xy.x) - qy * w_xy;
}

// consumer accel from a stage quat (raw, 1/M deferred).
__device__ __forceinline__ void acc_q(float qx, float qy, float qz, float qw,
                                      float T2, float TmG,
                                      v2& a_xy, float& az) {
  v2 t_xy = T2 * mk2(qy, -qx);
  a_xy = qw * t_xy + qz * mk2(-t_xy.y, t_xy.x);
  az   = TmG - T2 * (qx * qx + qy * qy);
}

// one producer RK4 step (bit-identical to R9's producer body); writes the
// 5 float4 fields for this step at dst[f*64].
__device__ __forceinline__ void prod_step(
    float4 u, v2& q_xy, v2& q_zw, v2& o_xy, float& oz, float4* dst) {
  float m20 = u.x * u.x, m21 = u.y * u.y, m22 = u.z * u.z, m23 = u.w * u.w;
  float sa = m20 + m21, sb = m22 + m23;
  float tq1 = kKTA * (sb - sa);
  float tq2 = kKTA * ((m21 + m22) - (m20 + m23));
  float tq3 = kKC  * ((m20 + m22) - (m21 + m23));
  tq1 = __builtin_amdgcn_fmed3f(tq1, -kTq0, kTq0);
  tq2 = __builtin_amdgcn_fmed3f(tq2, -kTq1, kTq1);
  tq3 = __builtin_amdgcn_fmed3f(tq3, -kTq2, kTq2);
  v2    s_xy = mk2(tq1 * kInvJx, tq2 * kInvJx);
  float wdz  = tq3 * kInvJz;          // stage-invariant (Jx==Jy)
  float ozh  = fmaf(kH,  wdz, oz);
  float ozf  = fmaf(kDT, wdz, oz);

  v2 qd1_xy, qd1_zw, wd1;
  dyn_q(q_xy, q_zw, o_xy, oz, s_xy, qd1_xy, qd1_zw, wd1);
  v2 q2_xy = q_xy + kHq * qd1_xy, q2_zw = q_zw + kHq * qd1_zw;
  renorm(q2_xy, q2_zw);
  v2 o2 = o_xy + kH * wd1;
  v2 qd2_xy, qd2_zw, wd2;
  dyn_q(q2_xy, q2_zw, o2, ozh, s_xy, qd2_xy, qd2_zw, wd2);
  v2 q3_xy = q_xy + kHq * qd2_xy, q3_zw = q_zw + kHq * qd2_zw;
  renorm(q3_xy, q3_zw);
  v2 o3 = o_xy + kH * wd2;
  v2 qd3_xy, qd3_zw, wd3;
  dyn_q(q3_xy, q3_zw, o3, ozh, s_xy, qd3_xy, qd3_zw, wd3);
  v2 q4_xy = q_xy + kDTq * qd3_xy, q4_zw = q_zw + kDTq * qd3_zw;
  renorm(q4_xy, q4_zw);
  v2 o4 = o_xy + kDT * wd3;
  v2 qd4_xy, qd4_zw, wd4;
  dyn_q(q4_xy, q4_zw, o4, ozf, s_xy, qd4_xy, qd4_zw, wd4);

  v2 wsum23 = wd2 + wd3;
  o_xy = o_xy + kDT6 * ((wd1 + wsum23) + (wsum23 + wd4));
  oz = ozf;
  v2 qxy23 = qd2_xy + qd3_xy;
  q_xy = q_xy + kDT6q * ((qd1_xy + qxy23) + (qxy23 + qd4_xy));
  v2 qzw23 = qd2_zw + qd3_zw;
  q_zw = q_zw + kDT6q * ((qd1_zw + qzw23) + (qzw23 + qd4_zw));
  renorm(q_xy, q_zw);

  dst[0 * 64] = make_float4(q2_xy.x, q2_xy.y, q2_zw.x, q2_zw.y);
  dst[1 * 64] = make_float4(q3_xy.x, q3_xy.y, q3_zw.x, q3_zw.y);
  dst[2 * 64] = make_float4(q4_xy.x, q4_xy.y, q4_zw.x, q4_zw.y);
  dst[3 * 64] = make_float4(q_xy.x, q_xy.y, q_zw.x, q_zw.y);
  dst[4 * 64] = make_float4(o_xy.x, o_xy.y, oz, 0.0f);
}

// one consumer step (bit-identical to R9's consumer body).
__device__ __forceinline__ void cons_step(
    float4 u, const float4* src,
    v2& p_xy, float& pz, v2& v_xy, float& vz,
    float& qpx, float& qpy, float& qpz, float& qpw,
    float4* ovp) {
  float m20 = u.x * u.x, m21 = u.y * u.y, m22 = u.z * u.z, m23 = u.w * u.w;
  float T  = fminf(kKT * ((m20 + m21) + (m22 + m23)), kTmax);
  float T2 = T + T, TmG = T - kMG;

  float4 Q2 = src[0 * 64];
  float4 Q3 = src[1 * 64];
  float4 Q4 = src[2 * 64];
  float4 QN = src[3 * 64];
  float4 OM = src[4 * 64];

  v2 a1, a2, a3, a4; float az1, az2, az3, az4;
  acc_q(qpx, qpy, qpz, qpw, T2, TmG, a1, az1);
  acc_q(Q2.x, Q2.y, Q2.z, Q2.w, T2, TmG, a2, az2);
  acc_q(Q3.x, Q3.y, Q3.z, Q3.w, T2, TmG, a3, az3);
  acc_q(Q4.x, Q4.y, Q4.z, Q4.w, T2, TmG, a4, az4);

  v2 t23 = a2 + a3;
  v2 Apos = a1 + t23;
  v2 Avel = Apos + t23 + a4;
  p_xy = p_xy + kDT * v_xy;  p_xy = p_xy + kPC * Apos;
  float az23 = az2 + az3;
  float Aposz = az1 + az23;
  float Avelz = Aposz + az23 + az4;
  pz = fmaf(kDT, vz, pz);  pz = fmaf(kPC, Aposz, pz);
  v_xy = v_xy + kVC * Avel;
  vz   = fmaf(kVC, Avelz, vz);

  float rx, ry, rz;
  quat_to_so3_fast(QN.x, QN.y, QN.z, QN.w, rx, ry, rz);
  ovp[0] = make_float4(p_xy.x, p_xy.y, pz, v_xy.x);
  ovp[1] = make_float4(v_xy.y, vz, rx, ry);
  ovp[2] = make_float4(rz, OM.x, OM.y, OM.z);

  qpx = QN.x; qpy = QN.y; qpz = QN.z; qpw = QN.w;
}

__global__ __launch_bounds__(128) void quad_rk4_kernel(
    const float* __restrict__ x0,
    const float* __restrict__ u_seq,
    float* __restrict__ out) {
  // [slot 0/1][step 0..3][field 0..4][lane] float4 = 40KB
  __shared__ float4 lds4[2 * 4 * 5 * 64];

  const int lane = threadIdx.x & 63;
  const int wid  = threadIdx.x >> 6;
  const int b    = blockIdx.x * 64 + lane;

  const float4* xv = reinterpret_cast<const float4*>(x0) + (size_t)b * 3;
  float4 s0 = xv[0], s1 = xv[1], s2 = xv[2];
  const float4* uv = reinterpret_cast<const float4*>(u_seq) + (size_t)b * kN;

  if (wid == 0) {
    // ================= PRODUCER: q / omega chain =================
    v2 o_xy = mk2(s2.y, s2.z);  float oz = s2.w;
    float qx0, qy0, qz0, qw0;
    so3_to_quat_init(s1.z, s1.w, s2.x, qx0, qy0, qz0, qw0);
    v2 q_xy = mk2(qx0, qy0), q_zw = mk2(qz0, qw0);

    float4 ug0 = uv[0], ug1 = uv[1], ug2 = uv[2], ug3 = uv[3];

    for (int g = 0; g < kN / 4; ++g) {
      int gn4 = (g < kN / 4 - 1) ? (g + 1) * 4 : (kN - 4);
      float4 un0 = uv[gn4 + 0], un1 = uv[gn4 + 1],
             un2 = uv[gn4 + 2], un3 = uv[gn4 + 3];

      float4* dst = &lds4[(g & 1) * 1280 + lane];
      prod_step(ug0, q_xy, q_zw, o_xy, oz, dst + 0 * 320);
      prod_step(ug1, q_xy, q_zw, o_xy, oz, dst + 1 * 320);
      prod_step(ug2, q_xy, q_zw, o_xy, oz, dst + 2 * 320);
      prod_step(ug3, q_xy, q_zw, o_xy, oz, dst + 3 * 320);
      __syncthreads();   // slot (g&1) ready; consumer drains it while we
                         // fill slot ((g+1)&1); we reuse (g&1) only after
                         // the NEXT barrier -> race-free double buffer.
      ug0 = un0; ug1 = un1; ug2 = un2; ug3 = un3;
    }
  } else {
    // ============ CONSUMER: accel / p / v / logmap / stores ============
    v2 p_xy = mk2(s0.x, s0.y);  float pz = s0.z;
    v2 v_xy = mk2(s0.w, s1.x);  float vz = s1.y;
    float qpx, qpy, qpz, qpw;   // quat at start of current step
    so3_to_quat_init(s1.z, s1.w, s2.x, qpx, qpy, qpz, qpw);

    float4* ov = reinterpret_cast<float4*>(out) + (size_t)b * kN * 3;
    float4 ug0 = uv[0], ug1 = uv[1], ug2 = uv[2], ug3 = uv[3];

    for (int g = 0; g < kN / 4; ++g) {
      int gn4 = (g < kN / 4 - 1) ? (g + 1) * 4 : (kN - 4);
      float4 un0 = uv[gn4 + 0], un1 = uv[gn4 + 1],
             un2 = uv[gn4 + 2], un3 = uv[gn4 + 3];

      __syncthreads();   // wait for producer's slot (g&1)
      const float4* src = &lds4[(g & 1) * 1280 + lane];
      float4* ovp = ov + (size_t)(g * 4) * 3;
      cons_step(ug0, src + 0 * 320, p_xy, pz, v_xy, vz, qpx, qpy, qpz, qpw, ovp + 0);
      cons_step(ug1, src + 1 * 320, p_xy, pz, v_xy, vz, qpx, qpy, qpz, qpw, ovp + 3);
      cons_step(ug2, src + 2 * 320, p_xy, pz, v_xy, vz, qpx, qpy, qpz, qpw, ovp + 6);
      cons_step(ug3, src + 3 * 320, p_xy, pz, v_xy, vz, qpx, qpy, qpz, qpw, ovp + 9);
      ug0 = un0; ug1 = un1; ug2 = un2; ug3 = un3;
    }
  }
}

extern "C" void kernel_launch(void* const* d_in, const int* in_sizes, int n_in,
                              void* d_out, int out_size, void* d_ws, size_t ws_size,
                              hipStream_t stream) {
  const float* x0    = (const float*)d_in[0];   // (8192, 12)
  const float* u_seq = (const float*)d_in[1];   // (8192, 256, 4)
  float*       out   = (float*)d_out;           // (8192, 256, 12)
  (void)in_sizes; (void)n_in; (void)out_size; (void)d_ws; (void)ws_size;

  dim3 block(128);            // wave0 = producer, wave1 = consumer
  dim3 grid(kB / 64);         // 128 blocks, 64 trajectories each
  quad_rk4_kernel<<<grid, block, 0, stream>>>(x0, u_seq, out);
}

// Round 8
// 188.698 us; speedup vs baseline: 1.5616x; 1.1021x over previous
//
#include <hip/hip_runtime.h>
#include <math.h>

// PhysQuadModel: batched RK4 rollout of quadrotor dynamics.
// Ladder (rocprof): R6 192 | R7 125 (single-wave floor) | R8 203 (pair-pack)
//   | R9 140 (2-wave split, 1 barrier/step) | R10 136 (inst shave regressed)
//   | R11 114 (2-wave split, K=4 batched barriers) <- best.
// Decomposition from R9/R11: sync ~319 cyc/barrier (amortized /4), producer
// stream ~994 cyc/step = the wall. Lone-wave cadence ~7 cyc/inst regardless
// of ILP -> only lever: move insts OFF the longest wave.
// R12 (this; resubmit after infra failure): 3-WAVE PIPELINE over K=4 groups,
//   1 barrier/slot (66 slots):
//   wave0: omega+tau chain (independent of q!) ships stage-omegas + T.
//   wave1: quat chain (reads stage omegas) ships q2,q3,q4,qN.  <- critical
//   wave2: accels + p/v + logmap + stores (no u loads; T from LDS).
//   omega buf 3 slots (lag-1 + lag-2 readers), quat buf 2 slots; 80KB LDS.
//   Math bit-identical to R11 (absmax 0.3125 expected).

namespace {
constexpr int   kB    = 8192;
constexpr int   kN    = 256;
constexpr float kDT   = 0.01f;
constexpr float kMG   = 0.033f * 9.81f;        // M*G
constexpr float kTmax = 1.9f * 0.033f * 9.81f; // 0.6150870
constexpr float kKT   = 3.8e-08f;
constexpr float kKC   = 3.8e-11f;
constexpr float kKTA  = kKT * 0.04f;           // KT*ARM
constexpr float kInvM = 1.0f / 0.033f;
constexpr float kJx   = 1.4e-05f, kJz = 2.17e-05f;
constexpr float kInvJx = 1.0f / 1.4e-05f;
constexpr float kInvJz = 1.0f / 2.17e-05f;
constexpr float kA    = (kJz - kJx) * kInvJx;  // 0.55 (Jx==Jy)
constexpr float kTq0  = 0.009f, kTq1 = 0.009f, kTq2 = 0.002f;
constexpr float kH    = 0.005f;                // 0.5*dt   (omega euler)
constexpr float kHq   = 0.0025f;               // 0.5*dt*0.5 (qd' = 2*qd)
constexpr float kDTq  = 0.005f;                // dt*0.5   (stage-4 quat)
constexpr float kDT6  = 0.0016666667f;         // dt/6
constexpr float kDT6q = 0.5f * kDT6;           // dt/12
constexpr float kVC   = kDT6 * kInvM;          // raw accel -> vel
constexpr float kPC   = kDT6 * kDT * kInvM;    // raw accel -> pos
}

typedef float v2 __attribute__((ext_vector_type(2)));

__device__ __forceinline__ v2 mk2(float a, float b) { v2 r; r.x = a; r.y = b; return r; }
__device__ __forceinline__ float fast_rcp(float x) { return __builtin_amdgcn_rcpf(x); }
__device__ __forceinline__ float fast_rsq(float x) { return __builtin_amdgcn_rsqf(x); }

// atan2 for y >= 0, result in [0, pi]. Minimax atan poly on [0,1], err ~1e-5.
__device__ __forceinline__ float atan2_pos(float y, float x) {
  float axx = fabsf(x);
  float mn  = fminf(y, axx);
  float mx  = fmaxf(y, axx);
  float t   = mn * fast_rcp(mx);
  float t2  = t * t;
  float p = fmaf(t2, -0.01172120f, 0.05265332f);
  p = fmaf(t2, p, -0.11643287f);
  p = fmaf(t2, p, 0.19354346f);
  p = fmaf(t2, p, -0.33262347f);
  p = fmaf(t2, p, 0.99997726f);
  p *= t;
  p = (y > axx) ? (1.5707963268f - p) : p;
  p = (x < 0.0f) ? (3.1415926536f - p) : p;
  return p;
}

// accurate, used ONCE per trajectory at init
__device__ __forceinline__ void so3_to_quat_init(float rx, float ry, float rz,
                                                 float& qx, float& qy, float& qz, float& qw) {
  float theta = sqrtf(rx * rx + ry * ry + rz * rz);
  float half  = 0.5f * theta;
  float s     = sinf(half);
  float c     = cosf(half);
  float k     = s / (theta + 1e-8f);
  bool  small = theta < 1e-6f;
  k  = small ? 0.5f : k;
  qw = small ? 1.0f : c;
  qx = k * rx; qy = k * ry; qz = k * rz;
}

// log map, output-only path (wave2)
__device__ __forceinline__ void quat_to_so3_fast(float qx, float qy, float qz, float qw,
                                                 float& rx, float& ry, float& rz) {
  float nv2 = qx * qx + qy * qy + qz * qz;
  float nv  = nv2 * fast_rsq(fmaxf(nv2, 1e-20f));   // sqrt(nv2), safe at 0
  float wc  = fminf(fmaxf(qw, -0.999999f), 0.999999f);
  float ang = 2.0f * atan2_pos(nv, wc);
  float k   = ang * fast_rcp(nv + 1e-6f);
  k = (nv < 1e-6f) ? 2.0f : k;
  rx = k * qx; ry = k * qy; rz = k * qz;
}

// Newton renorm from y0=1 (|q|^2 = 1+eps): no transcendental.
__device__ __forceinline__ void renorm(v2& a, v2& b) {
  v2 s = a * a + b * b;
  float c = 1.5f - 0.5f * (s.x + s.y);
  a *= c; b *= c;
}

// quat derivative (x2): same formulas as R11's dyn_q minus the omega part.
__device__ __forceinline__ void qd_calc(
    v2 q_xy, v2 q_zw, v2 w_xy, float wz, v2& qd_xy, v2& qd_zw) {
  float qx = q_xy.x, qy = q_xy.y, qz = q_zw.x, qw = q_zw.y;
  v2 aq = mk2(qy, -qx);
  v2 pw = mk2(-w_xy.y, w_xy.x);
  qd_xy = qw * w_xy + wz * aq + qz * pw;
  qd_zw = wz * mk2(qw, -qz) + qx * mk2(w_xy.y, -w_xy.x) - qy * w_xy;
}

// accel from a stage quat (raw, 1/M deferred).
__device__ __forceinline__ void acc_q(float qx, float qy, float qz, float qw,
                                      float T2, float TmG,
                                      v2& a_xy, float& az) {
  v2 t_xy = T2 * mk2(qy, -qx);
  a_xy = qw * t_xy + qz * mk2(-t_xy.y, t_xy.x);
  az   = TmG - T2 * (qx * qx + qy * qy);
}

// ---------------- wave0: omega + tau, one RK4 step -----------------
// ships: F0=(o1x,o1y,oz,ozh) F1=(o2x,o2y,o3x,o3y) F2=(o4x,o4y,ozf,T)
//        F3=(oNx,oNy,ozN,0)
__device__ __forceinline__ void omega_step(
    float4 u, v2& o_xy, float& oz, float4* dst) {
  float m20 = u.x * u.x, m21 = u.y * u.y, m22 = u.z * u.z, m23 = u.w * u.w;
  float sa = m20 + m21, sb = m22 + m23;
  float T   = fminf(kKT * (sa + sb), kTmax);
  float tq1 = kKTA * (sb - sa);
  float tq2 = kKTA * ((m21 + m22) - (m20 + m23));
  float tq3 = kKC  * ((m20 + m22) - (m21 + m23));
  tq1 = __builtin_amdgcn_fmed3f(tq1, -kTq0, kTq0);
  tq2 = __builtin_amdgcn_fmed3f(tq2, -kTq1, kTq1);
  tq3 = __builtin_amdgcn_fmed3f(tq3, -kTq2, kTq2);
  v2    s_xy = mk2(tq1 * kInvJx, tq2 * kInvJx);
  float wdz  = tq3 * kInvJz;          // stage-invariant (Jx==Jy)
  float ozh  = fmaf(kH,  wdz, oz);
  float ozf  = fmaf(kDT, wdz, oz);
  v2 wd1 = s_xy + (kA * oz ) * mk2(-o_xy.y, o_xy.x);
  v2 o2  = o_xy + kH * wd1;
  v2 wd2 = s_xy + (kA * ozh) * mk2(-o2.y, o2.x);
  v2 o3  = o_xy + kH * wd2;
  v2 wd3 = s_xy + (kA * ozh) * mk2(-o3.y, o3.x);
  v2 o4  = o_xy + kDT * wd3;
  v2 wd4 = s_xy + (kA * ozf) * mk2(-o4.y, o4.x);
  dst[0 * 64] = make_float4(o_xy.x, o_xy.y, oz, ozh);
  dst[1 * 64] = make_float4(o2.x, o2.y, o3.x, o3.y);
  dst[2 * 64] = make_float4(o4.x, o4.y, ozf, T);
  v2 ws = wd2 + wd3;
  o_xy = o_xy + kDT6 * ((wd1 + ws) + (ws + wd4));
  oz = ozf;
  dst[3 * 64] = make_float4(o_xy.x, o_xy.y, oz, 0.0f);
}

// ---------------- wave1: quat chain, one RK4 step ------------------
// reads omega F0..F2; ships q2,q3,q4,qN.
__device__ __forceinline__ void quat_step(
    const float4* src, v2& q_xy, v2& q_zw, float4* dst) {
  float4 F0 = src[0 * 64], F1 = src[1 * 64], F2 = src[2 * 64];
  v2 o1 = mk2(F0.x, F0.y); float oz1 = F0.z, ozh = F0.w;
  v2 o2 = mk2(F1.x, F1.y), o3 = mk2(F1.z, F1.w);
  v2 o4 = mk2(F2.x, F2.y); float ozf = F2.z;

  v2 qd1_xy, qd1_zw;
  qd_calc(q_xy, q_zw, o1, oz1, qd1_xy, qd1_zw);
  v2 q2_xy = q_xy + kHq * qd1_xy, q2_zw = q_zw + kHq * qd1_zw;
  renorm(q2_xy, q2_zw);
  v2 qd2_xy, qd2_zw;
  qd_calc(q2_xy, q2_zw, o2, ozh, qd2_xy, qd2_zw);
  v2 q3_xy = q_xy + kHq * qd2_xy, q3_zw = q_zw + kHq * qd2_zw;
  renorm(q3_xy, q3_zw);
  v2 qd3_xy, qd3_zw;
  qd_calc(q3_xy, q3_zw, o3, ozh, qd3_xy, qd3_zw);
  v2 q4_xy = q_xy + kDTq * qd3_xy, q4_zw = q_zw + kDTq * qd3_zw;
  renorm(q4_xy, q4_zw);
  v2 qd4_xy, qd4_zw;
  qd_calc(q4_xy, q4_zw, o4, ozf, qd4_xy, qd4_zw);

  dst[0 * 64] = make_float4(q2_xy.x, q2_xy.y, q2_zw.x, q2_zw.y);
  dst[1 * 64] = make_float4(q3_xy.x, q3_xy.y, q3_zw.x, q3_zw.y);
  dst[2 * 64] = make_float4(q4_xy.x, q4_xy.y, q4_zw.x, q4_zw.y);
  v2 qxy23 = qd2_xy + qd3_xy;
  q_xy = q_xy + kDT6q * ((qd1_xy + qxy23) + (qxy23 + qd4_xy));
  v2 qzw23 = qd2_zw + qd3_zw;
  q_zw = q_zw + kDT6q * ((qd1_zw + qzw23) + (qzw23 + qd4_zw));
  renorm(q_xy, q_zw);
  dst[3 * 64] = make_float4(q_xy.x, q_xy.y, q_zw.x, q_zw.y);
}

// ---------------- wave2: accel / p / v / logmap / stores -----------
__device__ __forceinline__ void cons_step(
    const float4* qsrc, const float4* osrc,
    v2& p_xy, float& pz, v2& v_xy, float& vz,
    float& qpx, float& qpy, float& qpz, float& qpw,
    float4* ovp) {
  float4 Q2 = qsrc[0 * 64], Q3 = qsrc[1 * 64], Q4 = qsrc[2 * 64], QN = qsrc[3 * 64];
  float4 F2 = osrc[2 * 64], OM = osrc[3 * 64];
  float T  = F2.w;
  float T2 = T + T, TmG = T - kMG;

  v2 a1, a2, a3, a4; float az1, az2, az3, az4;
  acc_q(qpx, qpy, qpz, qpw, T2, TmG, a1, az1);
  acc_q(Q2.x, Q2.y, Q2.z, Q2.w, T2, TmG, a2, az2);
  acc_q(Q3.x, Q3.y, Q3.z, Q3.w, T2, TmG, a3, az3);
  acc_q(Q4.x, Q4.y, Q4.z, Q4.w, T2, TmG, a4, az4);

  v2 t23 = a2 + a3;
  v2 Apos = a1 + t23;
  v2 Avel = Apos + t23 + a4;
  p_xy = p_xy + kDT * v_xy;  p_xy = p_xy + kPC * Apos;
  float az23 = az2 + az3;
  float Aposz = az1 + az23;
  float Avelz = Aposz + az23 + az4;
  pz = fmaf(kDT, vz, pz);  pz = fmaf(kPC, Aposz, pz);
  v_xy = v_xy + kVC * Avel;
  vz   = fmaf(kVC, Avelz, vz);

  float rx, ry, rz;
  quat_to_so3_fast(QN.x, QN.y, QN.z, QN.w, rx, ry, rz);
  ovp[0] = make_float4(p_xy.x, p_xy.y, pz, v_xy.x);
  ovp[1] = make_float4(v_xy.y, vz, rx, ry);
  ovp[2] = make_float4(rz, OM.x, OM.y, OM.z);

  qpx = QN.x; qpy = QN.y; qpz = QN.z; qpw = QN.w;
}

__global__ __launch_bounds__(192) void quad_rk4_kernel(
    const float* __restrict__ x0,
    const float* __restrict__ u_seq,
    float* __restrict__ out) {
  // omega buf: [slot3][step4][field4][lane64] float4 = 48KB (lag-1 + lag-2 readers)
  // quat  buf: [slot2][step4][field4][lane64] float4 = 32KB
  __shared__ float4 obuf[3 * 4 * 4 * 64];
  __shared__ float4 qbuf[2 * 4 * 4 * 64];

  const int lane = threadIdx.x & 63;
  const int wid  = threadIdx.x >> 6;
  const int b    = blockIdx.x * 64 + lane;

  const float4* xv = reinterpret_cast<const float4*>(x0) + (size_t)b * 3;
  float4 s0 = xv[0], s1 = xv[1], s2 = xv[2];
  const float4* uv = reinterpret_cast<const float4*>(u_seq) + (size_t)b * kN;

  // per-wave persistent state (each wave touches only its own)
  v2 o_xy; float oz = 0.0f;                       // wave0
  float4 ug0, ug1, ug2, ug3;
  v2 q_xy, q_zw;                                  // wave1
  v2 p_xy, v_xy; float pz = 0.0f, vz = 0.0f;      // wave2
  float qpx = 0.0f, qpy = 0.0f, qpz = 0.0f, qpw = 1.0f;
  float4* ov = reinterpret_cast<float4*>(out) + (size_t)b * kN * 3;

  if (wid == 0) {
    o_xy = mk2(s2.y, s2.z); oz = s2.w;
    ug0 = uv[0]; ug1 = uv[1]; ug2 = uv[2]; ug3 = uv[3];
  } else if (wid == 1) {
    float a, bb, c, d;
    so3_to_quat_init(s1.z, s1.w, s2.x, a, bb, c, d);
    q_xy = mk2(a, bb); q_zw = mk2(c, d);
  } else {
    p_xy = mk2(s0.x, s0.y); pz = s0.z;
    v_xy = mk2(s0.w, s1.x); vz = s1.y;
    so3_to_quat_init(s1.z, s1.w, s2.x, qpx, qpy, qpz, qpw);
  }

  constexpr int kG = kN / 4;           // 64 groups of 4 steps
  for (int s = 0; s < kG + 2; ++s) {
    if (wid == 0) {
      if (s < kG) {
        int gn = (s + 1 < kG) ? (s + 1) * 4 : (kG - 1) * 4;
        float4 un0 = uv[gn + 0], un1 = uv[gn + 1],
               un2 = uv[gn + 2], un3 = uv[gn + 3];
        float4* dst = &obuf[(s % 3) * 1024 + lane];
        omega_step(ug0, o_xy, oz, dst + 0 * 256);
        omega_step(ug1, o_xy, oz, dst + 1 * 256);
        omega_step(ug2, o_xy, oz, dst + 2 * 256);
        omega_step(ug3, o_xy, oz, dst + 3 * 256);
        ug0 = un0; ug1 = un1; ug2 = un2; ug3 = un3;
      }
    } else if (wid == 1) {
      if (s >= 1 && s <= kG) {
        int g = s - 1;
        const float4* src = &obuf[(g % 3) * 1024 + lane];
        float4*       dst = &qbuf[(g & 1) * 1024 + lane];
        quat_step(src + 0 * 256, q_xy, q_zw, dst + 0 * 256);
        quat_step(src + 1 * 256, q_xy, q_zw, dst + 1 * 256);
        quat_step(src + 2 * 256, q_xy, q_zw, dst + 2 * 256);
        quat_step(src + 3 * 256, q_xy, q_zw, dst + 3 * 256);
      }
    } else {
      if (s >= 2) {
        int g = s - 2;
        const float4* qsrc = &qbuf[(g & 1) * 1024 + lane];
        const float4* osrc = &obuf[(g % 3) * 1024 + lane];
        float4* ovp = ov + (size_t)(g * 4) * 3;
        cons_step(qsrc + 0 * 256, osrc + 0 * 256, p_xy, pz, v_xy, vz,
                  qpx, qpy, qpz, qpw, ovp + 0);
        cons_step(qsrc + 1 * 256, osrc + 1 * 256, p_xy, pz, v_xy, vz,
                  qpx, qpy, qpz, qpw, ovp + 3);
        cons_step(qsrc + 2 * 256, osrc + 2 * 256, p_xy, pz, v_xy, vz,
                  qpx, qpy, qpz, qpw, ovp + 6);
        cons_step(qsrc + 3 * 256, osrc + 3 * 256, p_xy, pz, v_xy, vz,
                  qpx, qpy, qpz, qpw, ovp + 9);
      }
    }
    __syncthreads();   // one barrier per slot; slot reuse analysis in header
  }
}

extern "C" void kernel_launch(void* const* d_in, const int* in_sizes, int n_in,
                              void* d_out, int out_size, void* d_ws, size_t ws_size,
                              hipStream_t stream) {
  const float* x0    = (const float*)d_in[0];   // (8192, 12)
  const float* u_seq = (const float*)d_in[1];   // (8192, 256, 4)
  float*       out   = (float*)d_out;           // (8192, 256, 12)
  (void)in_sizes; (void)n_in; (void)out_size; (void)d_ws; (void)ws_size;

  dim3 block(192);            // wave0 omega | wave1 quat | wave2 consumer
  dim3 grid(kB / 64);         // 128 blocks, 64 trajectories each
  quad_rk4_kernel<<<grid, block, 0, stream>>>(x0, u_seq, out);
}

// Round 9
// 179.463 us; speedup vs baseline: 1.6420x; 1.0515x over previous
//
#include <hip/hip_runtime.h>
#include <math.h>

// PhysQuadModel: batched RK4 rollout of quadrotor dynamics.
// Ladder (rocprof): R6 192 | R7 125 | R8 203 | R9 140 | R10 136 | R11 114
//   | R12 95 (3-wave pipeline: omega -> quat -> consumer, K=4, 1 barrier/slot).
// Model (validated R9->R12): wall/step = critical-wave stream x ~6-7 cyc/inst
//   + ~80 cyc amortized sync. R12 measured 890 cyc/step, waves ~50/85/85.
// R13 (this): 4-WAVE pipeline. Split consumer: w2 = accels + p/v + ov0 store
//   (~55), w3 = logmap + ov1/ov2 stores (~32). Drop 3 stage renorms on the
//   quat wave (R10a proved numerics: passed, absmax 0.3125) -> critical w1
//   ~66 inst/step. Slot s: w0 group s | w1 s-1 | w2 s-2 | w3 s-3; 67 slots.
//   obuf 4 slots (lag-3 reader), qbuf 3 (lag-2), vbuf 2 (lag-1) = 120KB LDS.

namespace {
constexpr int   kB    = 8192;
constexpr int   kN    = 256;
constexpr float kDT   = 0.01f;
constexpr float kMG   = 0.033f * 9.81f;        // M*G
constexpr float kTmax = 1.9f * 0.033f * 9.81f; // 0.6150870
constexpr float kKT   = 3.8e-08f;
constexpr float kKC   = 3.8e-11f;
constexpr float kKTA  = kKT * 0.04f;           // KT*ARM
constexpr float kInvM = 1.0f / 0.033f;
constexpr float kJx   = 1.4e-05f, kJz = 2.17e-05f;
constexpr float kInvJx = 1.0f / 1.4e-05f;
constexpr float kInvJz = 1.0f / 2.17e-05f;
constexpr float kA    = (kJz - kJx) * kInvJx;  // 0.55 (Jx==Jy)
constexpr float kTq0  = 0.009f, kTq1 = 0.009f, kTq2 = 0.002f;
constexpr float kH    = 0.005f;                // 0.5*dt   (omega euler)
constexpr float kHq   = 0.0025f;               // 0.5*dt*0.5 (qd' = 2*qd)
constexpr float kDTq  = 0.005f;                // dt*0.5   (stage-4 quat)
constexpr float kDT6  = 0.0016666667f;         // dt/6
constexpr float kDT6q = 0.5f * kDT6;           // dt/12
constexpr float kVC   = kDT6 * kInvM;          // raw accel -> vel
constexpr float kPC   = kDT6 * kDT * kInvM;    // raw accel -> pos
}

typedef float v2 __attribute__((ext_vector_type(2)));

__device__ __forceinline__ v2 mk2(float a, float b) { v2 r; r.x = a; r.y = b; return r; }
__device__ __forceinline__ float fast_rcp(float x) { return __builtin_amdgcn_rcpf(x); }
__device__ __forceinline__ float fast_rsq(float x) { return __builtin_amdgcn_rsqf(x); }

// atan2 for y >= 0, result in [0, pi]. Minimax atan poly on [0,1], err ~1e-5.
__device__ __forceinline__ float atan2_pos(float y, float x) {
  float axx = fabsf(x);
  float mn  = fminf(y, axx);
  float mx  = fmaxf(y, axx);
  float t   = mn * fast_rcp(mx);
  float t2  = t * t;
  float p = fmaf(t2, -0.01172120f, 0.05265332f);
  p = fmaf(t2, p, -0.11643287f);
  p = fmaf(t2, p, 0.19354346f);
  p = fmaf(t2, p, -0.33262347f);
  p = fmaf(t2, p, 0.99997726f);
  p *= t;
  p = (y > axx) ? (1.5707963268f - p) : p;
  p = (x < 0.0f) ? (3.1415926536f - p) : p;
  return p;
}

// accurate, used ONCE per trajectory at init
__device__ __forceinline__ void so3_to_quat_init(float rx, float ry, float rz,
                                                 float& qx, float& qy, float& qz, float& qw) {
  float theta = sqrtf(rx * rx + ry * ry + rz * rz);
  float half  = 0.5f * theta;
  float s     = sinf(half);
  float c     = cosf(half);
  float k     = s / (theta + 1e-8f);
  bool  small = theta < 1e-6f;
  k  = small ? 0.5f : k;
  qw = small ? 1.0f : c;
  qx = k * rx; qy = k * ry; qz = k * rz;
}

// log map, output-only path (w3)
__device__ __forceinline__ void quat_to_so3_fast(float qx, float qy, float qz, float qw,
                                                 float& rx, float& ry, float& rz) {
  float nv2 = qx * qx + qy * qy + qz * qz;
  float nv  = nv2 * fast_rsq(fmaxf(nv2, 1e-20f));   // sqrt(nv2), safe at 0
  float wc  = fminf(fmaxf(qw, -0.999999f), 0.999999f);
  float ang = 2.0f * atan2_pos(nv, wc);
  float k   = ang * fast_rcp(nv + 1e-6f);
  k = (nv < 1e-6f) ? 2.0f : k;
  rx = k * qx; ry = k * qy; rz = k * qz;
}

// Newton renorm from y0=1 (|q|^2 = 1+eps): no transcendental.
__device__ __forceinline__ void renorm(v2& a, v2& b) {
  v2 s = a * a + b * b;
  float c = 1.5f - 0.5f * (s.x + s.y);
  a *= c; b *= c;
}

// quat derivative (x2)
__device__ __forceinline__ void qd_calc(
    v2 q_xy, v2 q_zw, v2 w_xy, float wz, v2& qd_xy, v2& qd_zw) {
  float qx = q_xy.x, qy = q_xy.y, qz = q_zw.x, qw = q_zw.y;
  v2 aq = mk2(qy, -qx);
  v2 pw = mk2(-w_xy.y, w_xy.x);
  qd_xy = qw * w_xy + wz * aq + qz * pw;
  qd_zw = wz * mk2(qw, -qz) + qx * mk2(w_xy.y, -w_xy.x) - qy * w_xy;
}

// accel from a stage quat (raw, 1/M deferred).
__device__ __forceinline__ void acc_q(float qx, float qy, float qz, float qw,
                                      float T2, float TmG,
                                      v2& a_xy, float& az) {
  v2 t_xy = T2 * mk2(qy, -qx);
  a_xy = qw * t_xy + qz * mk2(-t_xy.y, t_xy.x);
  az   = TmG - T2 * (qx * qx + qy * qy);
}

// ---------------- w0: omega + tau, one RK4 step (same as R12) -------
// ships: F0=(o1x,o1y,oz,ozh) F1=(o2x,o2y,o3x,o3y) F2=(o4x,o4y,ozf,T)
//        F3=(oNx,oNy,ozN,0)
__device__ __forceinline__ void omega_step(
    float4 u, v2& o_xy, float& oz, float4* dst) {
  float m20 = u.x * u.x, m21 = u.y * u.y, m22 = u.z * u.z, m23 = u.w * u.w;
  float sa = m20 + m21, sb = m22 + m23;
  float T   = fminf(kKT * (sa + sb), kTmax);
  float tq1 = kKTA * (sb - sa);
  float tq2 = kKTA * ((m21 + m22) - (m20 + m23));
  float tq3 = kKC  * ((m20 + m22) - (m21 + m23));
  tq1 = __builtin_amdgcn_fmed3f(tq1, -kTq0, kTq0);
  tq2 = __builtin_amdgcn_fmed3f(tq2, -kTq1, kTq1);
  tq3 = __builtin_amdgcn_fmed3f(tq3, -kTq2, kTq2);
  v2    s_xy = mk2(tq1 * kInvJx, tq2 * kInvJx);
  float wdz  = tq3 * kInvJz;          // stage-invariant (Jx==Jy)
  float ozh  = fmaf(kH,  wdz, oz);
  float ozf  = fmaf(kDT, wdz, oz);
  v2 wd1 = s_xy + (kA * oz ) * mk2(-o_xy.y, o_xy.x);
  v2 o2  = o_xy + kH * wd1;
  v2 wd2 = s_xy + (kA * ozh) * mk2(-o2.y, o2.x);
  v2 o3  = o_xy + kH * wd2;
  v2 wd3 = s_xy + (kA * ozh) * mk2(-o3.y, o3.x);
  v2 o4  = o_xy + kDT * wd3;
  v2 wd4 = s_xy + (kA * ozf) * mk2(-o4.y, o4.x);
  dst[0 * 64] = make_float4(o_xy.x, o_xy.y, oz, ozh);
  dst[1 * 64] = make_float4(o2.x, o2.y, o3.x, o3.y);
  dst[2 * 64] = make_float4(o4.x, o4.y, ozf, T);
  v2 ws = wd2 + wd3;
  o_xy = o_xy + kDT6 * ((wd1 + ws) + (ws + wd4));
  oz = ozf;
  dst[3 * 64] = make_float4(o_xy.x, o_xy.y, oz, 0.0f);
}

// ---------------- w1: quat chain, NO stage renorms (R10a-proven) ----
__device__ __forceinline__ void quat_step_nr(
    const float4* src, v2& q_xy, v2& q_zw, float4* dst) {
  float4 F0 = src[0 * 64], F1 = src[1 * 64], F2 = src[2 * 64];
  v2 o1 = mk2(F0.x, F0.y); float oz1 = F0.z, ozh = F0.w;
  v2 o2 = mk2(F1.x, F1.y), o3 = mk2(F1.z, F1.w);
  v2 o4 = mk2(F2.x, F2.y); float ozf = F2.z;

  v2 qd1_xy, qd1_zw;
  qd_calc(q_xy, q_zw, o1, oz1, qd1_xy, qd1_zw);
  v2 q2_xy = q_xy + kHq * qd1_xy, q2_zw = q_zw + kHq * qd1_zw;
  v2 qd2_xy, qd2_zw;
  qd_calc(q2_xy, q2_zw, o2, ozh, qd2_xy, qd2_zw);
  v2 q3_xy = q_xy + kHq * qd2_xy, q3_zw = q_zw + kHq * qd2_zw;
  v2 qd3_xy, qd3_zw;
  qd_calc(q3_xy, q3_zw, o3, ozh, qd3_xy, qd3_zw);
  v2 q4_xy = q_xy + kDTq * qd3_xy, q4_zw = q_zw + kDTq * qd3_zw;
  v2 qd4_xy, qd4_zw;
  qd_calc(q4_xy, q4_zw, o4, ozf, qd4_xy, qd4_zw);

  dst[0 * 64] = make_float4(q2_xy.x, q2_xy.y, q2_zw.x, q2_zw.y);
  dst[1 * 64] = make_float4(q3_xy.x, q3_xy.y, q3_zw.x, q3_zw.y);
  dst[2 * 64] = make_float4(q4_xy.x, q4_xy.y, q4_zw.x, q4_zw.y);
  v2 qxy23 = qd2_xy + qd3_xy;
  q_xy = q_xy + kDT6q * ((qd1_xy + qxy23) + (qxy23 + qd4_xy));
  v2 qzw23 = qd2_zw + qd3_zw;
  q_zw = q_zw + kDT6q * ((qd1_zw + qzw23) + (qzw23 + qd4_zw));
  renorm(q_xy, q_zw);               // loop-carried renorm kept
  dst[3 * 64] = make_float4(q_xy.x, q_xy.y, q_zw.x, q_zw.y);
}

// ---------------- w2: accels + p/v + ov0 store; ships (vy,vz) -------
__device__ __forceinline__ void accpv_step(
    const float4* qsrc, const float4* osrc, float4* vdst,
    v2& p_xy, float& pz, v2& v_xy, float& vz,
    float& qpx, float& qpy, float& qpz, float& qpw,
    float4* ovp) {
  float4 Q2 = qsrc[0 * 64], Q3 = qsrc[1 * 64], Q4 = qsrc[2 * 64], QN = qsrc[3 * 64];
  float T  = osrc[2 * 64].w;
  float T2 = T + T, TmG = T - kMG;

  v2 a1, a2, a3, a4; float az1, az2, az3, az4;
  acc_q(qpx, qpy, qpz, qpw, T2, TmG, a1, az1);
  acc_q(Q2.x, Q2.y, Q2.z, Q2.w, T2, TmG, a2, az2);
  acc_q(Q3.x, Q3.y, Q3.z, Q3.w, T2, TmG, a3, az3);
  acc_q(Q4.x, Q4.y, Q4.z, Q4.w, T2, TmG, a4, az4);

  v2 t23 = a2 + a3;
  v2 Apos = a1 + t23;
  v2 Avel = Apos + t23 + a4;
  p_xy = p_xy + kDT * v_xy;  p_xy = p_xy + kPC * Apos;
  float az23 = az2 + az3;
  float Aposz = az1 + az23;
  float Avelz = Aposz + az23 + az4;
  pz = fmaf(kDT, vz, pz);  pz = fmaf(kPC, Aposz, pz);
  v_xy = v_xy + kVC * Avel;
  vz   = fmaf(kVC, Avelz, vz);

  ovp[0]   = make_float4(p_xy.x, p_xy.y, pz, v_xy.x);
  vdst[0]  = make_float4(v_xy.y, vz, 0.0f, 0.0f);

  qpx = QN.x; qpy = QN.y; qpz = QN.z; qpw = QN.w;
}

// ---------------- w3: logmap + ov1/ov2 stores -----------------------
__device__ __forceinline__ void logst_step(
    const float4* qsrc, const float4* osrc, const float4* vsrc, float4* ovp) {
  float4 QN = qsrc[3 * 64];
  float4 OM = osrc[3 * 64];
  float4 V  = vsrc[0];
  float rx, ry, rz;
  quat_to_so3_fast(QN.x, QN.y, QN.z, QN.w, rx, ry, rz);
  ovp[1] = make_float4(V.x, V.y, rx, ry);
  ovp[2] = make_float4(rz, OM.x, OM.y, OM.z);
}

__global__ __launch_bounds__(256) void quad_rk4_kernel(
    const float* __restrict__ x0,
    const float* __restrict__ u_seq,
    float* __restrict__ out) {
  // obuf [slot4][step4][field4][lane64]  = 64KB (lag-3 reader w3)
  // qbuf [slot3][step4][field4][lane64]  = 48KB (lag-2 reader w3)
  // vbuf [slot2][step4][lane64]          =  8KB (lag-1 reader w3)
  __shared__ float4 obuf[4 * 4 * 4 * 64];
  __shared__ float4 qbuf[3 * 4 * 4 * 64];
  __shared__ float4 vbuf[2 * 4 * 64];

  const int lane = threadIdx.x & 63;
  const int wid  = threadIdx.x >> 6;
  const int b    = blockIdx.x * 64 + lane;

  const float4* xv = reinterpret_cast<const float4*>(x0) + (size_t)b * 3;
  float4 s0 = xv[0], s1 = xv[1], s2 = xv[2];
  const float4* uv = reinterpret_cast<const float4*>(u_seq) + (size_t)b * kN;
  float4* ov = reinterpret_cast<float4*>(out) + (size_t)b * kN * 3;

  // per-wave persistent state
  v2 o_xy; float oz = 0.0f;                       // w0
  float4 ug0, ug1, ug2, ug3;
  v2 q_xy, q_zw;                                  // w1
  v2 p_xy, v_xy; float pz = 0.0f, vz = 0.0f;      // w2
  float qpx = 0.0f, qpy = 0.0f, qpz = 0.0f, qpw = 1.0f;

  if (wid == 0) {
    o_xy = mk2(s2.y, s2.z); oz = s2.w;
    ug0 = uv[0]; ug1 = uv[1]; ug2 = uv[2]; ug3 = uv[3];
  } else if (wid == 1) {
    float a, bb, c, d;
    so3_to_quat_init(s1.z, s1.w, s2.x, a, bb, c, d);
    q_xy = mk2(a, bb); q_zw = mk2(c, d);
  } else if (wid == 2) {
    p_xy = mk2(s0.x, s0.y); pz = s0.z;
    v_xy = mk2(s0.w, s1.x); vz = s1.y;
    so3_to_quat_init(s1.z, s1.w, s2.x, qpx, qpy, qpz, qpw);
  }

  constexpr int kG = kN / 4;           // 64 groups of 4 steps
  for (int s = 0; s < kG + 3; ++s) {
    if (wid == 0) {
      if (s < kG) {
        int gn = (s + 1 < kG) ? (s + 1) * 4 : (kG - 1) * 4;
        float4 un0 = uv[gn + 0], un1 = uv[gn + 1],
               un2 = uv[gn + 2], un3 = uv[gn + 3];
        float4* dst = &obuf[(s & 3) * 1024 + lane];
        omega_step(ug0, o_xy, oz, dst + 0 * 256);
        omega_step(ug1, o_xy, oz, dst + 1 * 256);
        omega_step(ug2, o_xy, oz, dst + 2 * 256);
        omega_step(ug3, o_xy, oz, dst + 3 * 256);
        ug0 = un0; ug1 = un1; ug2 = un2; ug3 = un3;
      }
    } else if (wid == 1) {
      if (s >= 1 && s <= kG) {
        int g = s - 1;
        const float4* src = &obuf[(g & 3) * 1024 + lane];
        float4*       dst = &qbuf[(g % 3) * 1024 + lane];
        quat_step_nr(src + 0 * 256, q_xy, q_zw, dst + 0 * 256);
        quat_step_nr(src + 1 * 256, q_xy, q_zw, dst + 1 * 256);
        quat_step_nr(src + 2 * 256, q_xy, q_zw, dst + 2 * 256);
        quat_step_nr(src + 3 * 256, q_xy, q_zw, dst + 3 * 256);
      }
    } else if (wid == 2) {
      if (s >= 2 && s <= kG + 1) {
        int g = s - 2;
        const float4* qsrc = &qbuf[(g % 3) * 1024 + lane];
        const float4* osrc = &obuf[(g & 3) * 1024 + lane];
        float4*       vdst = &vbuf[(g & 1) * 256 + lane];
        float4* ovp = ov + (size_t)(g * 4) * 3;
        accpv_step(qsrc + 0 * 256, osrc + 0 * 256, vdst + 0 * 64,
                   p_xy, pz, v_xy, vz, qpx, qpy, qpz, qpw, ovp + 0);
        accpv_step(qsrc + 1 * 256, osrc + 1 * 256, vdst + 1 * 64,
                   p_xy, pz, v_xy, vz, qpx, qpy, qpz, qpw, ovp + 3);
        accpv_step(qsrc + 2 * 256, osrc + 2 * 256, vdst + 2 * 64,
                   p_xy, pz, v_xy, vz, qpx, qpy, qpz, qpw, ovp + 6);
        accpv_step(qsrc + 3 * 256, osrc + 3 * 256, vdst + 3 * 64,
                   p_xy, pz, v_xy, vz, qpx, qpy, qpz, qpw, ovp + 9);
      }
    } else {
      if (s >= 3) {
        int g = s - 3;
        const float4* qsrc = &qbuf[(g % 3) * 1024 + lane];
        const float4* osrc = &obuf[(g & 3) * 1024 + lane];
        const float4* vsrc = &vbuf[(g & 1) * 256 + lane];
        float4* ovp = ov + (size_t)(g * 4) * 3;
        logst_step(qsrc + 0 * 256, osrc + 0 * 256, vsrc + 0 * 64, ovp + 0);
        logst_step(qsrc + 1 * 256, osrc + 1 * 256, vsrc + 1 * 64, ovp + 3);
        logst_step(qsrc + 2 * 256, osrc + 2 * 256, vsrc + 2 * 64, ovp + 6);
        logst_step(qsrc + 3 * 256, osrc + 3 * 256, vsrc + 3 * 64, ovp + 9);
      }
    }
    __syncthreads();   // uniform: every wave hits every barrier
  }
}

extern "C" void kernel_launch(void* const* d_in, const int* in_sizes, int n_in,
                              void* d_out, int out_size, void* d_ws, size_t ws_size,
                              hipStream_t stream) {
  const float* x0    = (const float*)d_in[0];   // (8192, 12)
  const float* u_seq = (const float*)d_in[1];   // (8192, 256, 4)
  float*       out   = (float*)d_out;           // (8192, 256, 12)
  (void)in_sizes; (void)n_in; (void)out_size; (void)d_ws; (void)ws_size;

  dim3 block(256);            // w0 omega | w1 quat | w2 acc+pv | w3 log+store
  dim3 grid(kB / 64);         // 128 blocks, 64 trajectories each
  quad_rk4_kernel<<<grid, block, 0, stream>>>(x0, u_seq, out);
}